// Round 3
// baseline (1476.175 us; speedup 1.0000x reference)
//
#include <hip/hip_runtime.h>
#include <stdint.h>

#define B      256
#define DIN    700
#define T      250
#define H      1024
#define DOUT   20
#define NW_IN  11     // u64 words for 700 input bits
#define NW_INP 12     // padded
#define NW_H   16     // u64 words for 1024 hidden bits
#define LMAX   160    // padded list length (max n ~110 for 10% of 700)

typedef unsigned long long u64;

// ---------------- prep: transpose weights ----------------
__global__ void prep_weights(const float* __restrict__ W_hid,
                             const float* __restrict__ W_out,
                             float* __restrict__ Wt,
                             float* __restrict__ WoT) {
    int idx = blockIdx.x * 256 + threadIdx.x;
    if (blockIdx.x < 2800) {
        int d = idx / H;
        int h = idx - d * H;
        Wt[idx] = W_hid[h * DIN + d];
    } else {
        int i = idx - 2800 * 256;   // 0..20479
        int h = i / DOUT;
        int o = i - h * DOUT;
        WoT[i] = W_out[o * H + h];
    }
}

// ---------------- prep: bitpack spikes ----------------
__global__ void prep_bits(const float* __restrict__ spk,
                          u64* __restrict__ bits) {
    int b  = blockIdx.x >> 2;
    int wc = blockIdx.x & 3;
    int t  = threadIdx.x;
    if (t >= T) return;
    int w0 = wc * 3;
    int w1 = (wc == 3) ? NW_IN : w0 + 3;
    const float* base = spk + (size_t)b * DIN * T + t;
    for (int w = w0; w < w1; ++w) {
        u64 m = 0;
#pragma unroll
        for (int j = 0; j < 64; ++j) {
            int d = (w << 6) + j;
            if (d < DIN) {
                float x = base[(size_t)d * T];
                m |= (u64)(x > 0.5f) << j;
            }
        }
        bits[((size_t)b * T + t) * NW_INP + w] = m;
    }
}

// ---------------- prep: expand bitmasks to padded u16 index lists ----------------
// One thread per (b,t) row. Ascending j. Padded to LMAX with j=700 (zero row).
__global__ void prep_lists(const u64* __restrict__ bits,
                           unsigned short* __restrict__ lists,
                           unsigned short* __restrict__ nrow) {
    int row = blockIdx.x * 256 + threadIdx.x;
    if (row >= B * T) return;
    const u64* wp = bits + (size_t)row * NW_INP;
    unsigned short* lp = lists + (size_t)row * LMAX;
    int pos = 0;
#pragma unroll
    for (int k = 0; k < NW_IN; ++k) {
        u64 m = wp[k];
        while (m) {
            int bb = __builtin_ctzll(m);
            m &= m - 1;
            if (pos < LMAX) lp[pos] = (unsigned short)((k << 6) + bb);
            ++pos;
        }
    }
    int n = pos < LMAX ? pos : LMAX;
    nrow[row] = (unsigned short)n;
    for (int p = n; p < LMAX; ++p) lp[p] = 700;   // zero-row padding
}

// ---------------- hidden layer: LDS-staged Wt slice + fused scan ----------------
// Block = (h-slice of 32 cols, pair of b). LDS: Wt slice [701][32] floats
// (row 700 = zeros) + cur[2][250][32]. 4 waves x 8 groups of 8 lanes;
// each group gathers one (b,t) row from LDS (its own list, ascending j,
// sequential fp32 per lane's 4 h -> bit-exact). Scan fused: waves 0/1 run
// the recurrence for b0/b1 over their 32 h, writing u32 half-words of
// hsbits in the original plain layout.
__global__ void __launch_bounds__(256)
hidden_slice(const unsigned short* __restrict__ lists,
             const unsigned short* __restrict__ nrow,
             const float* __restrict__ Wt,
             const float* __restrict__ hs0,
             const float* __restrict__ hv0,
             u64* __restrict__ hsbits) {
    __shared__ float wlds[701 * 32];      // 89,728 B
    __shared__ float cur[2][250 * 32];    // 64,000 B

    int s   = blockIdx.x;        // 0..31 h-slice
    int bp  = blockIdx.y;        // 0..127 b-pair
    int tid = threadIdx.x;
    int wv  = tid >> 6;
    int lane = tid & 63;

    // ---- stage Wt slice (linear LDS, coalesced-ish 128B segments) ----
    {
        int jr = lane >> 3, li = lane & 7;
        for (int base_j = wv * 8; base_j < 704; base_j += 32) {
            int j = base_j + jr;
            if (j < 700) {
                float4 v = *(const float4*)(Wt + (size_t)j * H + s * 32 + li * 4);
                *(float4*)&wlds[j * 32 + li * 4] = v;
            }
        }
        if (tid < 32) wlds[700 * 32 + tid] = 0.0f;
    }
    __syncthreads();

    // ---- gather: 500 rows (2 b's x 250 t), 32 rows per pass ----
    int g   = lane >> 3;
    int li4 = (lane & 7) * 4;
    for (int pass = 0; pass < 16; ++pass) {
        int r  = pass * 32 + wv * 8 + g;          // 0..511
        int rv = (r < 500) ? r : 0;               // dummy -> row 0 (harmless)
        int bi = rv >= 250 ? 1 : 0;
        int t  = rv - 250 * bi;
        int row = (bp * 2 + bi) * T + t;
        int n = (r < 500) ? (int)nrow[row] : 0;

        // wave-max n over the 8 groups (lane bits 3..5)
        int nm = n;
        nm = max(nm, __shfl_xor(nm, 8));
        nm = max(nm, __shfl_xor(nm, 16));
        nm = max(nm, __shfl_xor(nm, 32));
        nm = (nm + 7) & ~7;                       // lists padded with zero row

        const unsigned short* jp = lists + (size_t)row * LMAX;
        float a0 = 0.0f, a1 = 0.0f, a2 = 0.0f, a3 = 0.0f;

        if (nm > 0) {
            uint4 w4 = *(const uint4*)jp;
            for (int i = 0; i < nm; i += 8) {
                uint4 nw = (i + 8 < LMAX) ? *(const uint4*)(jp + i + 8) : w4;
                int j0 = w4.x & 0xffff, j1 = w4.x >> 16;
                int j2 = w4.y & 0xffff, j3 = w4.y >> 16;
                int j4 = w4.z & 0xffff, j5 = w4.z >> 16;
                int j6 = w4.w & 0xffff, j7 = w4.w >> 16;
                float4 v0 = *(const float4*)&wlds[j0 * 32 + li4];
                float4 v1 = *(const float4*)&wlds[j1 * 32 + li4];
                float4 v2 = *(const float4*)&wlds[j2 * 32 + li4];
                float4 v3 = *(const float4*)&wlds[j3 * 32 + li4];
                float4 v4 = *(const float4*)&wlds[j4 * 32 + li4];
                float4 v5 = *(const float4*)&wlds[j5 * 32 + li4];
                float4 v6 = *(const float4*)&wlds[j6 * 32 + li4];
                float4 v7 = *(const float4*)&wlds[j7 * 32 + li4];
                a0 += v0.x; a1 += v0.y; a2 += v0.z; a3 += v0.w;
                a0 += v1.x; a1 += v1.y; a2 += v1.z; a3 += v1.w;
                a0 += v2.x; a1 += v2.y; a2 += v2.z; a3 += v2.w;
                a0 += v3.x; a1 += v3.y; a2 += v3.z; a3 += v3.w;
                a0 += v4.x; a1 += v4.y; a2 += v4.z; a3 += v4.w;
                a0 += v5.x; a1 += v5.y; a2 += v5.z; a3 += v5.w;
                a0 += v6.x; a1 += v6.y; a2 += v6.z; a3 += v6.w;
                a0 += v7.x; a1 += v7.y; a2 += v7.z; a3 += v7.w;
                w4 = nw;
            }
        }
        if (r < 500) {
            float4 o; o.x = a0; o.y = a1; o.z = a2; o.w = a3;
            *(float4*)&cur[bi][t * 32 + li4] = o;
        }
    }
    __syncthreads();

    // ---- fused scan: wave wv (<2) handles b = bp*2+wv over its 32 h ----
    if (wv < 2) {
        int l = lane & 31;                 // lanes 32-63 mirror 0-31
        int b = bp * 2 + wv;
        int h = s * 32 + l;
        float keep = hv0[b * H + h] * 0.5f * (1.0f - hs0[b * H + h]);
        unsigned* hp = (unsigned*)hsbits;
        float c = cur[wv][l];
        for (int t = 0; t < T; ++t) {
            float cn = (t + 1 < T) ? cur[wv][(t + 1) * 32 + l] : 0.0f;
            float hv = keep + c;
            bool sp = hv > 0.5f;
            keep = sp ? 0.0f : hv * 0.5f;
            u64 ball = __ballot(sp);       // bits 32-63 mirror 0-31
            if (lane == 0)
                hp[(((size_t)b * T + t) * NW_H + (s >> 1)) * 2 + (s & 1)] = (unsigned)ball;
            c = cn;
        }
    }
}

// ---------------- fallback: round-0 fused hidden kernel (proven) ----------------
__global__ void __launch_bounds__(1024)
hidden_fused(const u64* __restrict__ bits,
             const float* __restrict__ Wt,
             const float* __restrict__ hs0,
             const float* __restrict__ hv0,
             u64* __restrict__ hsbits) {
    __shared__ int idx_l[2][256];

    int b = blockIdx.x;
    int h = threadIdx.x;
    int wv   = h >> 6;
    int lane = h & 63;

    float keep = hv0[b * H + h] * 0.5f * (1.0f - hs0[b * H + h]);

    const u64* bb = bits + (size_t)b * T * NW_INP;

    for (int t = 0; t < T; ++t) {
        const u64* wp = bb + (size_t)t * NW_INP;
        u64 w[NW_IN];
#pragma unroll
        for (int k = 0; k < NW_IN; ++k) w[k] = wp[k];

        int base[NW_IN + 1];
        base[0] = 0;
#pragma unroll
        for (int k = 0; k < NW_IN; ++k) base[k + 1] = base[k] + __popcll(w[k]);
        int n = base[NW_IN];

        int buf = t & 1;
        if (wv < NW_IN) {
            u64 m = w[wv];
            if ((m >> lane) & 1ull) {
                int pos = base[wv] + __popcll(m & ((1ull << lane) - 1ull));
                idx_l[buf][pos] = (wv << 6) + lane;
            }
        }
        __syncthreads();

        const int* il = idx_l[buf];
        float cur2 = 0.0f;
        int i = 0;
        for (; i + 8 <= n; i += 8) {
            int j0 = il[i + 0], j1 = il[i + 1], j2 = il[i + 2], j3 = il[i + 3];
            int j4 = il[i + 4], j5 = il[i + 5], j6 = il[i + 6], j7 = il[i + 7];
            float v0 = Wt[(size_t)j0 * H + h];
            float v1 = Wt[(size_t)j1 * H + h];
            float v2 = Wt[(size_t)j2 * H + h];
            float v3 = Wt[(size_t)j3 * H + h];
            float v4 = Wt[(size_t)j4 * H + h];
            float v5 = Wt[(size_t)j5 * H + h];
            float v6 = Wt[(size_t)j6 * H + h];
            float v7 = Wt[(size_t)j7 * H + h];
            cur2 += v0; cur2 += v1; cur2 += v2; cur2 += v3;
            cur2 += v4; cur2 += v5; cur2 += v6; cur2 += v7;
        }
        for (; i < n; ++i) cur2 += Wt[(size_t)il[i] * H + h];

        float hv = keep + cur2;
        bool sp = hv > 0.5f;
        keep = sp ? 0.0f : hv * 0.5f;
        u64 ball = __ballot(sp);
        if (lane == 0)
            hsbits[((size_t)b * T + t) * NW_H + wv] = ball;
    }
}

// ---------------- output currents: Iout[b*T+t][o] ----------------
__global__ void __launch_bounds__(256)
out_currents(const u64* __restrict__ hsbits,
             const float* __restrict__ WoT,
             float* __restrict__ Iout) {
    __shared__ int lidx[4][2][256];

    int wv   = threadIdx.x >> 6;
    int lane = threadIdx.x & 63;
    int row  = blockIdx.x * 4 + wv;   // < 64000 exactly

    const u64* wp = hsbits + (size_t)row * NW_H;

    float acc = 0.0f;
#pragma unroll
    for (int g = 0; g < 4; ++g) {
        u64 w[4];
#pragma unroll
        for (int k = 0; k < 4; ++k) w[k] = wp[g * 4 + k];

        int base[5];
        base[0] = 0;
#pragma unroll
        for (int k = 0; k < 4; ++k) base[k + 1] = base[k] + __popcll(w[k]);
        int n = base[4];

        int buf = g & 1;
#pragma unroll
        for (int k = 0; k < 4; ++k) {
            u64 m = w[k];
            if ((m >> lane) & 1ull) {
                int pos = base[k] + __popcll(m & ((1ull << lane) - 1ull));
                lidx[wv][buf][pos] = ((g * 4 + k) << 6) + lane;
            }
        }
        __syncthreads();

        const int* il = lidx[wv][buf];
        int i = 0;
        for (; i + 4 <= n; i += 4) {
            int j0 = il[i + 0], j1 = il[i + 1], j2 = il[i + 2], j3 = il[i + 3];
            if (lane < DOUT) {
                float v0 = WoT[(size_t)j0 * DOUT + lane];
                float v1 = WoT[(size_t)j1 * DOUT + lane];
                float v2 = WoT[(size_t)j2 * DOUT + lane];
                float v3 = WoT[(size_t)j3 * DOUT + lane];
                acc += v0; acc += v1; acc += v2; acc += v3;
            }
        }
        for (; i < n; ++i) {
            if (lane < DOUT) acc += WoT[(size_t)il[i] * DOUT + lane];
        }
    }
    if (lane < DOUT) Iout[(size_t)row * DOUT + lane] = acc;
}

// ---------------- output scan + spike count ----------------
__global__ void out_scan(const float* __restrict__ Iout,
                         const float* __restrict__ os0,
                         const float* __restrict__ ov0,
                         float* __restrict__ outp) {
    int idx = blockIdx.x * 256 + threadIdx.x;
    if (idx >= B * DOUT) return;
    int b = idx / DOUT;
    int o = idx - b * DOUT;

    float ov = ov0[idx];
    float os = os0[idx];
    float keep = ov * 0.5f * (1.0f - os);
    float cnt = 0.0f;
    const float* ip = Iout + (size_t)b * T * DOUT + o;
#pragma unroll 5
    for (int t = 0; t < T; ++t) {
        float v = keep + ip[(size_t)t * DOUT];
        float s = (v > 0.5f) ? 1.0f : 0.0f;
        cnt += s;
        keep = v * 0.5f * (1.0f - s);
    }
    outp[idx] = cnt;
}

extern "C" void kernel_launch(void* const* d_in, const int* in_sizes, int n_in,
                              void* d_out, int out_size, void* d_ws, size_t ws_size,
                              hipStream_t stream) {
    const float* spike = (const float*)d_in[0];   // [256][700][250]
    const float* W_hid = (const float*)d_in[1];   // [1024][700]
    const float* W_out = (const float*)d_in[2];   // [20][1024]
    const float* hs0   = (const float*)d_in[3];   // [256][1024]
    const float* hv0   = (const float*)d_in[4];
    const float* os0   = (const float*)d_in[5];   // [256][20]
    const float* ov0   = (const float*)d_in[6];
    float* outp = (float*)d_out;                  // [256][20]

    char* ws = (char*)d_ws;
    float*          Wt     = (float*)(ws);                      // 2,867,200 B
    float*          WoT    = (float*)(ws + 2867200);            //    81,920 B
    u64*            bits   = (u64*)  (ws + 2949120);            // 6,144,000 B
    u64*            hsbits = (u64*)  (ws + 9093120);            // 8,192,000 B
    float*          Iout   = (float*)(ws + 17285120);           // 5,120,000 B
    unsigned short* lists  = (unsigned short*)(ws + 22405120);  // 20,480,000 B
    unsigned short* nrow   = (unsigned short*)(ws + 42885120);  //   128,000 B
    const size_t need = 43013120;

    prep_weights<<<2880, 256, 0, stream>>>(W_hid, W_out, Wt, WoT);
    prep_bits<<<1024, 256, 0, stream>>>(spike, bits);

    if (ws_size >= need) {
        prep_lists<<<250, 256, 0, stream>>>(bits, lists, nrow);
        hidden_slice<<<dim3(32, 128), 256, 0, stream>>>(lists, nrow, Wt, hs0, hv0, hsbits);
    } else {
        hidden_fused<<<B, 1024, 0, stream>>>(bits, Wt, hs0, hv0, hsbits);
    }

    out_currents<<<16000, 256, 0, stream>>>(hsbits, WoT, Iout);
    out_scan<<<20, 256, 0, stream>>>(Iout, os0, ov0, outp);
}

// Round 4
// 1228.469 us; speedup vs baseline: 1.2016x; 1.2016x over previous
//
#include <hip/hip_runtime.h>
#include <stdint.h>

#define B      256
#define DIN    700
#define T      250
#define H      1024
#define DOUT   20
#define NW_IN  11     // u64 words for 700 input bits
#define NW_INP 12     // padded
#define NW_H   16     // u64 words for 1024 hidden bits
#define LMAX   160    // per-row list capacity (two padded sublists)
#define JSENT  44896  // sentinel pre-offset: local row 350 (zeros)

typedef unsigned long long u64;

// ---------------- prep: transpose weights ----------------
__global__ void prep_weights(const float* __restrict__ W_hid,
                             const float* __restrict__ W_out,
                             float* __restrict__ Wt,
                             float* __restrict__ WoT) {
    int idx = blockIdx.x * 256 + threadIdx.x;
    if (blockIdx.x < 2800) {
        int d = idx / H;
        int h = idx - d * H;
        Wt[idx] = W_hid[h * DIN + d];
    } else {
        int i = idx - 2800 * 256;   // 0..20479
        int h = i / DOUT;
        int o = i - h * DOUT;
        WoT[i] = W_out[o * H + h];
    }
}

// ---------------- prep: bitpack spikes ----------------
__global__ void prep_bits(const float* __restrict__ spk,
                          u64* __restrict__ bits) {
    int b  = blockIdx.x >> 2;
    int wc = blockIdx.x & 3;
    int t  = threadIdx.x;
    if (t >= T) return;
    int w0 = wc * 3;
    int w1 = (wc == 3) ? NW_IN : w0 + 3;
    const float* base = spk + (size_t)b * DIN * T + t;
    for (int w = w0; w < w1; ++w) {
        u64 m = 0;
#pragma unroll
        for (int j = 0; j < 64; ++j) {
            int d = (w << 6) + j;
            if (d < DIN) {
                float x = base[(size_t)d * T];
                m |= (u64)(x > 0.5f) << j;
            }
        }
        bits[((size_t)b * T + t) * NW_INP + w] = m;
    }
}

// ---------------- prep: two packed sublists of pre-swizzled LDS byte offsets ----
// Sublist A: j in [0,350), sublist B: j in [350,700) as local j-350. Each entry
// is pre = jl*128 + ((jl&7)<<4); lane address = pre ^ (li<<4). Each sublist is
// padded to a multiple of 8 with JSENT (row 350 = zeros). nrow packs the two
// chunk counts (u8 each).
__global__ void prep_lists(const u64* __restrict__ bits,
                           unsigned short* __restrict__ lists,
                           unsigned short* __restrict__ nrow) {
    int row = blockIdx.x * 256 + threadIdx.x;
    if (row >= B * T) return;
    const u64* wp = bits + (size_t)row * NW_INP;
    unsigned short* lp = lists + (size_t)row * LMAX;
    int pos = 0;
    // ---- A: words 0..4 full, word 5 bits 0..29 (j < 350) ----
#pragma unroll
    for (int k = 0; k < 6; ++k) {
        u64 m = wp[k];
        if (k == 5) m &= (1ull << 30) - 1ull;
        while (m) {
            int bb = __builtin_ctzll(m);
            m &= m - 1;
            int j = (k << 6) + bb;
            if (pos < LMAX) lp[pos] = (unsigned short)(j * 128 + ((j & 7) << 4));
            ++pos;
        }
    }
    int cA = (pos + 7) >> 3;
    while (pos < cA * 8 && pos < LMAX) lp[pos++] = JSENT;
    int posB0 = pos;
    // ---- B: word 5 bits 30.., words 6..10 (j >= 350, local = j-350) ----
#pragma unroll
    for (int k = 5; k < NW_IN; ++k) {
        u64 m = wp[k];
        if (k == 5) m &= ~((1ull << 30) - 1ull);
        while (m) {
            int bb = __builtin_ctzll(m);
            m &= m - 1;
            int jl = (k << 6) + bb - 350;
            if (pos < LMAX) lp[pos] = (unsigned short)(jl * 128 + ((jl & 7) << 4));
            ++pos;
        }
    }
    int cB = ((pos - posB0) + 7) >> 3;
    while (pos < LMAX) lp[pos++] = JSENT;
    nrow[row] = (unsigned short)(cA | (cB << 8));
}

// ---------------- hidden layer: swizzled LDS Wt slice, 2 j-passes, fused scan ----
// Block = (32-h slice s, batch b). LDS 77 KB -> 2 blocks/CU. 4 waves x 8 groups
// of 8 lanes; each group gathers one t-row per pass from the swizzled slice.
// Pass B continues pass A's running sum (same sequential ascending-j fp32 chain
// per h -> bit-exact). Fused scan writes u32 halves of hsbits (plain layout).
__global__ void __launch_bounds__(256, 2)
hidden_slice2(const unsigned short* __restrict__ lists,
              const unsigned short* __restrict__ nrow,
              const float* __restrict__ Wt,
              const float* __restrict__ hs0,
              const float* __restrict__ hv0,
              u64* __restrict__ hsbits) {
    __shared__ float wlds[351 * 32];   // 44,928 B (row 350 = zeros)
    __shared__ float cur[250 * 32];    // 32,000 B

    int s    = blockIdx.x;        // 0..31 h-slice
    int b    = blockIdx.y;        // 0..255
    int tid  = threadIdx.x;
    int wv   = tid >> 6;
    int lane = tid & 63;
    int g    = lane >> 3;
    int li   = lane & 7;
    int lxor = li << 4;

    for (int p = 0; p < 2; ++p) {
        // ---- stage half-Wt slice, swizzled: slot = li ^ (j&7) ----
        {
            int jr = tid >> 3;                 // 0..31
            int lis = tid & 7;
            for (int base_j = 0; base_j < 352; base_j += 32) {
                int j = base_j + jr;
                if (j < 351) {
                    float4 v;
                    if (j < 350)
                        v = *(const float4*)(Wt + (size_t)(p * 350 + j) * H + s * 32 + lis * 4);
                    else
                        v = make_float4(0.0f, 0.0f, 0.0f, 0.0f);
                    *(float4*)((char*)wlds + j * 128 + ((lis ^ (j & 7)) << 4)) = v;
                }
            }
        }
        __syncthreads();

        // ---- gather: 250 rows, 32 per sweep (4 waves x 8 groups) ----
        for (int sweep = 0; sweep < 8; ++sweep) {
            int r = sweep * 32 + wv * 8 + g;   // t
            if (r < 250) {
                int row = b * T + r;
                unsigned cc = nrow[row];
                int cA = cc & 0xff;
                int c  = p ? ((cc >> 8) & 0xff) : cA;
                const uint4* qp = (const uint4*)(lists + (size_t)row * LMAX + (p ? cA * 8 : 0));

                float a0, a1, a2, a3;
                if (p == 0) {
                    a0 = a1 = a2 = a3 = 0.0f;
                } else {
                    float4 cv = *(const float4*)((char*)cur + r * 128 + lxor);
                    a0 = cv.x; a1 = cv.y; a2 = cv.z; a3 = cv.w;
                }

                if (c > 0) {
                    uint4 w4 = qp[0];
                    int ch = 0;
                    for (;;) {
                        uint4 nw = (ch + 1 < c) ? qp[ch + 1] : w4;
                        int e0 = w4.x & 0xffff, e1 = w4.x >> 16;
                        int e2 = w4.y & 0xffff, e3 = w4.y >> 16;
                        int e4 = w4.z & 0xffff, e5 = w4.z >> 16;
                        int e6 = w4.w & 0xffff, e7 = w4.w >> 16;
                        float4 v0 = *(const float4*)((char*)wlds + (e0 ^ lxor));
                        float4 v1 = *(const float4*)((char*)wlds + (e1 ^ lxor));
                        float4 v2 = *(const float4*)((char*)wlds + (e2 ^ lxor));
                        float4 v3 = *(const float4*)((char*)wlds + (e3 ^ lxor));
                        float4 v4 = *(const float4*)((char*)wlds + (e4 ^ lxor));
                        float4 v5 = *(const float4*)((char*)wlds + (e5 ^ lxor));
                        float4 v6 = *(const float4*)((char*)wlds + (e6 ^ lxor));
                        float4 v7 = *(const float4*)((char*)wlds + (e7 ^ lxor));
                        a0 += v0.x; a1 += v0.y; a2 += v0.z; a3 += v0.w;
                        a0 += v1.x; a1 += v1.y; a2 += v1.z; a3 += v1.w;
                        a0 += v2.x; a1 += v2.y; a2 += v2.z; a3 += v2.w;
                        a0 += v3.x; a1 += v3.y; a2 += v3.z; a3 += v3.w;
                        a0 += v4.x; a1 += v4.y; a2 += v4.z; a3 += v4.w;
                        a0 += v5.x; a1 += v5.y; a2 += v5.z; a3 += v5.w;
                        a0 += v6.x; a1 += v6.y; a2 += v6.z; a3 += v6.w;
                        a0 += v7.x; a1 += v7.y; a2 += v7.z; a3 += v7.w;
                        ++ch;
                        if (ch >= c) break;
                        w4 = nw;
                    }
                }
                float4 o; o.x = a0; o.y = a1; o.z = a2; o.w = a3;
                *(float4*)((char*)cur + r * 128 + lxor) = o;
            }
        }
        __syncthreads();
    }

    // ---- fused scan: wave 0 (lanes 32-63 mirror), 32 h of this (s,b) ----
    if (wv == 0) {
        int l = lane & 31;
        int h = s * 32 + l;
        float keep = hv0[b * H + h] * 0.5f * (1.0f - hs0[b * H + h]);
        unsigned* hp = (unsigned*)hsbits;
        float c = cur[l];
        for (int t = 0; t < T; ++t) {
            float cn = (t + 1 < T) ? cur[(t + 1) * 32 + l] : 0.0f;
            float hv = keep + c;
            bool sp = hv > 0.5f;
            keep = sp ? 0.0f : hv * 0.5f;
            u64 ball = __ballot(sp);
            if (lane == 0)
                hp[(size_t)(b * T + t) * 32 + s] = (unsigned)ball;
            c = cn;
        }
    }
}

// ---------------- fallback: round-0 fused hidden kernel (proven) ----------------
__global__ void __launch_bounds__(1024)
hidden_fused(const u64* __restrict__ bits,
             const float* __restrict__ Wt,
             const float* __restrict__ hs0,
             const float* __restrict__ hv0,
             u64* __restrict__ hsbits) {
    __shared__ int idx_l[2][256];

    int b = blockIdx.x;
    int h = threadIdx.x;
    int wv   = h >> 6;
    int lane = h & 63;

    float keep = hv0[b * H + h] * 0.5f * (1.0f - hs0[b * H + h]);

    const u64* bb = bits + (size_t)b * T * NW_INP;

    for (int t = 0; t < T; ++t) {
        const u64* wp = bb + (size_t)t * NW_INP;
        u64 w[NW_IN];
#pragma unroll
        for (int k = 0; k < NW_IN; ++k) w[k] = wp[k];

        int base[NW_IN + 1];
        base[0] = 0;
#pragma unroll
        for (int k = 0; k < NW_IN; ++k) base[k + 1] = base[k] + __popcll(w[k]);
        int n = base[NW_IN];

        int buf = t & 1;
        if (wv < NW_IN) {
            u64 m = w[wv];
            if ((m >> lane) & 1ull) {
                int pos = base[wv] + __popcll(m & ((1ull << lane) - 1ull));
                idx_l[buf][pos] = (wv << 6) + lane;
            }
        }
        __syncthreads();

        const int* il = idx_l[buf];
        float cur2 = 0.0f;
        int i = 0;
        for (; i + 8 <= n; i += 8) {
            int j0 = il[i + 0], j1 = il[i + 1], j2 = il[i + 2], j3 = il[i + 3];
            int j4 = il[i + 4], j5 = il[i + 5], j6 = il[i + 6], j7 = il[i + 7];
            float v0 = Wt[(size_t)j0 * H + h];
            float v1 = Wt[(size_t)j1 * H + h];
            float v2 = Wt[(size_t)j2 * H + h];
            float v3 = Wt[(size_t)j3 * H + h];
            float v4 = Wt[(size_t)j4 * H + h];
            float v5 = Wt[(size_t)j5 * H + h];
            float v6 = Wt[(size_t)j6 * H + h];
            float v7 = Wt[(size_t)j7 * H + h];
            cur2 += v0; cur2 += v1; cur2 += v2; cur2 += v3;
            cur2 += v4; cur2 += v5; cur2 += v6; cur2 += v7;
        }
        for (; i < n; ++i) cur2 += Wt[(size_t)il[i] * H + h];

        float hv = keep + cur2;
        bool sp = hv > 0.5f;
        keep = sp ? 0.0f : hv * 0.5f;
        u64 ball = __ballot(sp);
        if (lane == 0)
            hsbits[((size_t)b * T + t) * NW_H + wv] = ball;
    }
}

// ---------------- output currents: Iout[b*T+t][o] ----------------
__global__ void __launch_bounds__(256)
out_currents(const u64* __restrict__ hsbits,
             const float* __restrict__ WoT,
             float* __restrict__ Iout) {
    __shared__ int lidx[4][2][256];

    int wv   = threadIdx.x >> 6;
    int lane = threadIdx.x & 63;
    int row  = blockIdx.x * 4 + wv;   // < 64000 exactly

    const u64* wp = hsbits + (size_t)row * NW_H;

    float acc = 0.0f;
#pragma unroll
    for (int g = 0; g < 4; ++g) {
        u64 w[4];
#pragma unroll
        for (int k = 0; k < 4; ++k) w[k] = wp[g * 4 + k];

        int base[5];
        base[0] = 0;
#pragma unroll
        for (int k = 0; k < 4; ++k) base[k + 1] = base[k] + __popcll(w[k]);
        int n = base[4];

        int buf = g & 1;
#pragma unroll
        for (int k = 0; k < 4; ++k) {
            u64 m = w[k];
            if ((m >> lane) & 1ull) {
                int pos = base[k] + __popcll(m & ((1ull << lane) - 1ull));
                lidx[wv][buf][pos] = ((g * 4 + k) << 6) + lane;
            }
        }
        __syncthreads();

        const int* il = lidx[wv][buf];
        int i = 0;
        for (; i + 4 <= n; i += 4) {
            int j0 = il[i + 0], j1 = il[i + 1], j2 = il[i + 2], j3 = il[i + 3];
            if (lane < DOUT) {
                float v0 = WoT[(size_t)j0 * DOUT + lane];
                float v1 = WoT[(size_t)j1 * DOUT + lane];
                float v2 = WoT[(size_t)j2 * DOUT + lane];
                float v3 = WoT[(size_t)j3 * DOUT + lane];
                acc += v0; acc += v1; acc += v2; acc += v3;
            }
        }
        for (; i < n; ++i) {
            if (lane < DOUT) acc += WoT[(size_t)il[i] * DOUT + lane];
        }
    }
    if (lane < DOUT) Iout[(size_t)row * DOUT + lane] = acc;
}

// ---------------- output scan + spike count ----------------
__global__ void out_scan(const float* __restrict__ Iout,
                         const float* __restrict__ os0,
                         const float* __restrict__ ov0,
                         float* __restrict__ outp) {
    int idx = blockIdx.x * 256 + threadIdx.x;
    if (idx >= B * DOUT) return;
    int b = idx / DOUT;
    int o = idx - b * DOUT;

    float ov = ov0[idx];
    float os = os0[idx];
    float keep = ov * 0.5f * (1.0f - os);
    float cnt = 0.0f;
    const float* ip = Iout + (size_t)b * T * DOUT + o;
#pragma unroll 5
    for (int t = 0; t < T; ++t) {
        float v = keep + ip[(size_t)t * DOUT];
        float s = (v > 0.5f) ? 1.0f : 0.0f;
        cnt += s;
        keep = v * 0.5f * (1.0f - s);
    }
    outp[idx] = cnt;
}

extern "C" void kernel_launch(void* const* d_in, const int* in_sizes, int n_in,
                              void* d_out, int out_size, void* d_ws, size_t ws_size,
                              hipStream_t stream) {
    const float* spike = (const float*)d_in[0];   // [256][700][250]
    const float* W_hid = (const float*)d_in[1];   // [1024][700]
    const float* W_out = (const float*)d_in[2];   // [20][1024]
    const float* hs0   = (const float*)d_in[3];   // [256][1024]
    const float* hv0   = (const float*)d_in[4];
    const float* os0   = (const float*)d_in[5];   // [256][20]
    const float* ov0   = (const float*)d_in[6];
    float* outp = (float*)d_out;                  // [256][20]

    char* ws = (char*)d_ws;
    float*          Wt     = (float*)(ws);                      // 2,867,200 B
    float*          WoT    = (float*)(ws + 2867200);            //    81,920 B
    u64*            bits   = (u64*)  (ws + 2949120);            // 6,144,000 B
    u64*            hsbits = (u64*)  (ws + 9093120);            // 8,192,000 B
    float*          Iout   = (float*)(ws + 17285120);           // 5,120,000 B
    unsigned short* lists  = (unsigned short*)(ws + 22405120);  // 20,480,000 B
    unsigned short* nrow   = (unsigned short*)(ws + 42885120);  //   128,000 B
    const size_t need = 43013120;

    prep_weights<<<2880, 256, 0, stream>>>(W_hid, W_out, Wt, WoT);
    prep_bits<<<1024, 256, 0, stream>>>(spike, bits);

    if (ws_size >= need) {
        prep_lists<<<250, 256, 0, stream>>>(bits, lists, nrow);
        hidden_slice2<<<dim3(32, 256), 256, 0, stream>>>(lists, nrow, Wt, hs0, hv0, hsbits);
    } else {
        hidden_fused<<<B, 1024, 0, stream>>>(bits, Wt, hs0, hv0, hsbits);
    }

    out_currents<<<16000, 256, 0, stream>>>(hsbits, WoT, Iout);
    out_scan<<<20, 256, 0, stream>>>(Iout, os0, ov0, outp);
}

// Round 5
// 1015.863 us; speedup vs baseline: 1.4531x; 1.2093x over previous
//
#include <hip/hip_runtime.h>
#include <stdint.h>

#define B      256
#define DIN    700
#define T      250
#define H      1024
#define DOUT   20
#define NW_IN  11     // u64 words for 700 input bits
#define NW_INP 12     // padded
#define NW_H   16     // u64 words for 1024 hidden bits
#define LMAX   160    // per-row list capacity (two padded sublists)
#define JSENT  44896  // sentinel pre-offset: local row 350 (zeros)

typedef unsigned long long u64;

// ---------------- prep: transpose weights ----------------
__global__ void prep_weights(const float* __restrict__ W_hid,
                             const float* __restrict__ W_out,
                             float* __restrict__ Wt,
                             float* __restrict__ WoT) {
    int idx = blockIdx.x * 256 + threadIdx.x;
    if (blockIdx.x < 2800) {
        int d = idx / H;
        int h = idx - d * H;
        Wt[idx] = W_hid[h * DIN + d];
    } else {
        int i = idx - 2800 * 256;   // 0..20479
        int h = i / DOUT;
        int o = i - h * DOUT;
        WoT[i] = W_out[o * H + h];
    }
}

// ---------------- prep: bitpack spikes ----------------
__global__ void prep_bits(const float* __restrict__ spk,
                          u64* __restrict__ bits) {
    int b  = blockIdx.x >> 2;
    int wc = blockIdx.x & 3;
    int t  = threadIdx.x;
    if (t >= T) return;
    int w0 = wc * 3;
    int w1 = (wc == 3) ? NW_IN : w0 + 3;
    const float* base = spk + (size_t)b * DIN * T + t;
    for (int w = w0; w < w1; ++w) {
        u64 m = 0;
#pragma unroll
        for (int j = 0; j < 64; ++j) {
            int d = (w << 6) + j;
            if (d < DIN) {
                float x = base[(size_t)d * T];
                m |= (u64)(x > 0.5f) << j;
            }
        }
        bits[((size_t)b * T + t) * NW_INP + w] = m;
    }
}

// ---------------- prep: two packed sublists of pre-swizzled LDS byte offsets ----
// Sublist A: j in [0,350), sublist B: j in [350,700) as local j-350. Each entry
// is pre = jl*128 + ((jl&7)<<4); lane address = pre ^ (li<<4). Each sublist is
// padded to a multiple of 8 with JSENT (row 350 = zeros). nrow packs the two
// chunk counts (u8 each).
__global__ void prep_lists(const u64* __restrict__ bits,
                           unsigned short* __restrict__ lists,
                           unsigned short* __restrict__ nrow) {
    int row = blockIdx.x * 256 + threadIdx.x;
    if (row >= B * T) return;
    const u64* wp = bits + (size_t)row * NW_INP;
    unsigned short* lp = lists + (size_t)row * LMAX;
    int pos = 0;
    // ---- A: words 0..4 full, word 5 bits 0..29 (j < 350) ----
#pragma unroll
    for (int k = 0; k < 6; ++k) {
        u64 m = wp[k];
        if (k == 5) m &= (1ull << 30) - 1ull;
        while (m) {
            int bb = __builtin_ctzll(m);
            m &= m - 1;
            int j = (k << 6) + bb;
            if (pos < LMAX) lp[pos] = (unsigned short)(j * 128 + ((j & 7) << 4));
            ++pos;
        }
    }
    int cA = (pos + 7) >> 3;
    while (pos < cA * 8 && pos < LMAX) lp[pos++] = JSENT;
    int posB0 = pos;
    // ---- B: word 5 bits 30.., words 6..10 (j >= 350, local = j-350) ----
#pragma unroll
    for (int k = 5; k < NW_IN; ++k) {
        u64 m = wp[k];
        if (k == 5) m &= ~((1ull << 30) - 1ull);
        while (m) {
            int bb = __builtin_ctzll(m);
            m &= m - 1;
            int jl = (k << 6) + bb - 350;
            if (pos < LMAX) lp[pos] = (unsigned short)(jl * 128 + ((jl & 7) << 4));
            ++pos;
        }
    }
    int cB = ((pos - posB0) + 7) >> 3;
    while (pos < LMAX) lp[pos++] = JSENT;
    nrow[row] = (unsigned short)(cA | (cB << 8));
}

// ---------------- hidden layer: swizzled LDS Wt slice, 2 j-passes, fused scan ----
// Block = (32-h slice s, batch b), 512 threads (8 waves) -> with 77 KB LDS this
// is 2 blocks/CU = 16 waves/CU = 4 waves/SIMD, enough TLP to saturate the LDS
// port. 64 8-lane groups gather one t-row each per sweep (4 sweeps/pass).
// Pass B continues pass A's running sum (sequential ascending-j fp32 chain per
// h -> bit-exact). Fused scan writes u32 halves of hsbits (plain layout).
__global__ void __launch_bounds__(512, 2)
hidden_slice2(const unsigned short* __restrict__ lists,
              const unsigned short* __restrict__ nrow,
              const float* __restrict__ Wt,
              const float* __restrict__ hs0,
              const float* __restrict__ hv0,
              u64* __restrict__ hsbits) {
    __shared__ float wlds[351 * 32];   // 44,928 B (row 350 = zeros)
    __shared__ float cur[250 * 32];    // 32,000 B

    int s    = blockIdx.x;        // 0..31 h-slice
    int b    = blockIdx.y;        // 0..255
    int tid  = threadIdx.x;
    int wv   = tid >> 6;
    int lane = tid & 63;
    int g    = lane >> 3;
    int li   = lane & 7;
    int lxor = li << 4;

    for (int p = 0; p < 2; ++p) {
        // ---- stage half-Wt slice, swizzled: slot = li ^ (j&7) ----
        {
            int jr  = tid >> 3;                // 0..63
            int lis = tid & 7;
#pragma unroll
            for (int base_j = 0; base_j < 384; base_j += 64) {
                int j = base_j + jr;
                if (j < 351) {
                    float4 v;
                    if (j < 350)
                        v = *(const float4*)(Wt + (size_t)(p * 350 + j) * H + s * 32 + lis * 4);
                    else
                        v = make_float4(0.0f, 0.0f, 0.0f, 0.0f);
                    *(float4*)((char*)wlds + j * 128 + ((lis ^ (j & 7)) << 4)) = v;
                }
            }
        }
        __syncthreads();

        // ---- gather: 250 rows, 64 per sweep (8 waves x 8 groups) ----
        for (int sweep = 0; sweep < 4; ++sweep) {
            int r = sweep * 64 + wv * 8 + g;   // t
            if (r < 250) {
                int row = b * T + r;
                unsigned cc = nrow[row];
                int cA = cc & 0xff;
                int c  = p ? ((cc >> 8) & 0xff) : cA;
                const uint4* qp = (const uint4*)(lists + (size_t)row * LMAX + (p ? cA * 8 : 0));

                float a0, a1, a2, a3;
                if (p == 0) {
                    a0 = a1 = a2 = a3 = 0.0f;
                } else {
                    float4 cv = *(const float4*)((char*)cur + r * 128 + lxor);
                    a0 = cv.x; a1 = cv.y; a2 = cv.z; a3 = cv.w;
                }

                if (c > 0) {
                    uint4 w4 = qp[0];
                    int ch = 0;
                    for (;;) {
                        uint4 nw = (ch + 1 < c) ? qp[ch + 1] : w4;
                        int e0 = w4.x & 0xffff, e1 = w4.x >> 16;
                        int e2 = w4.y & 0xffff, e3 = w4.y >> 16;
                        int e4 = w4.z & 0xffff, e5 = w4.z >> 16;
                        int e6 = w4.w & 0xffff, e7 = w4.w >> 16;
                        float4 v0 = *(const float4*)((char*)wlds + (e0 ^ lxor));
                        float4 v1 = *(const float4*)((char*)wlds + (e1 ^ lxor));
                        float4 v2 = *(const float4*)((char*)wlds + (e2 ^ lxor));
                        float4 v3 = *(const float4*)((char*)wlds + (e3 ^ lxor));
                        float4 v4 = *(const float4*)((char*)wlds + (e4 ^ lxor));
                        float4 v5 = *(const float4*)((char*)wlds + (e5 ^ lxor));
                        float4 v6 = *(const float4*)((char*)wlds + (e6 ^ lxor));
                        float4 v7 = *(const float4*)((char*)wlds + (e7 ^ lxor));
                        a0 += v0.x; a1 += v0.y; a2 += v0.z; a3 += v0.w;
                        a0 += v1.x; a1 += v1.y; a2 += v1.z; a3 += v1.w;
                        a0 += v2.x; a1 += v2.y; a2 += v2.z; a3 += v2.w;
                        a0 += v3.x; a1 += v3.y; a2 += v3.z; a3 += v3.w;
                        a0 += v4.x; a1 += v4.y; a2 += v4.z; a3 += v4.w;
                        a0 += v5.x; a1 += v5.y; a2 += v5.z; a3 += v5.w;
                        a0 += v6.x; a1 += v6.y; a2 += v6.z; a3 += v6.w;
                        a0 += v7.x; a1 += v7.y; a2 += v7.z; a3 += v7.w;
                        ++ch;
                        if (ch >= c) break;
                        w4 = nw;
                    }
                }
                float4 o; o.x = a0; o.y = a1; o.z = a2; o.w = a3;
                *(float4*)((char*)cur + r * 128 + lxor) = o;
            }
        }
        __syncthreads();
    }

    // ---- fused scan: wave 0 (lanes 32-63 mirror), 32 h of this (s,b) ----
    if (wv == 0) {
        int l = lane & 31;
        int h = s * 32 + l;
        float keep = hv0[b * H + h] * 0.5f * (1.0f - hs0[b * H + h]);
        unsigned* hp = (unsigned*)hsbits;
        float c = cur[l];
        for (int t = 0; t < T; ++t) {
            float cn = (t + 1 < T) ? cur[(t + 1) * 32 + l] : 0.0f;
            float hv = keep + c;
            bool sp = hv > 0.5f;
            keep = sp ? 0.0f : hv * 0.5f;
            u64 ball = __ballot(sp);
            if (lane == 0)
                hp[(size_t)(b * T + t) * 32 + s] = (unsigned)ball;
            c = cn;
        }
    }
}

// ---------------- fallback: round-0 fused hidden kernel (proven) ----------------
__global__ void __launch_bounds__(1024)
hidden_fused(const u64* __restrict__ bits,
             const float* __restrict__ Wt,
             const float* __restrict__ hs0,
             const float* __restrict__ hv0,
             u64* __restrict__ hsbits) {
    __shared__ int idx_l[2][256];

    int b = blockIdx.x;
    int h = threadIdx.x;
    int wv   = h >> 6;
    int lane = h & 63;

    float keep = hv0[b * H + h] * 0.5f * (1.0f - hs0[b * H + h]);

    const u64* bb = bits + (size_t)b * T * NW_INP;

    for (int t = 0; t < T; ++t) {
        const u64* wp = bb + (size_t)t * NW_INP;
        u64 w[NW_IN];
#pragma unroll
        for (int k = 0; k < NW_IN; ++k) w[k] = wp[k];

        int base[NW_IN + 1];
        base[0] = 0;
#pragma unroll
        for (int k = 0; k < NW_IN; ++k) base[k + 1] = base[k] + __popcll(w[k]);
        int n = base[NW_IN];

        int buf = t & 1;
        if (wv < NW_IN) {
            u64 m = w[wv];
            if ((m >> lane) & 1ull) {
                int pos = base[wv] + __popcll(m & ((1ull << lane) - 1ull));
                idx_l[buf][pos] = (wv << 6) + lane;
            }
        }
        __syncthreads();

        const int* il = idx_l[buf];
        float cur2 = 0.0f;
        int i = 0;
        for (; i + 8 <= n; i += 8) {
            int j0 = il[i + 0], j1 = il[i + 1], j2 = il[i + 2], j3 = il[i + 3];
            int j4 = il[i + 4], j5 = il[i + 5], j6 = il[i + 6], j7 = il[i + 7];
            float v0 = Wt[(size_t)j0 * H + h];
            float v1 = Wt[(size_t)j1 * H + h];
            float v2 = Wt[(size_t)j2 * H + h];
            float v3 = Wt[(size_t)j3 * H + h];
            float v4 = Wt[(size_t)j4 * H + h];
            float v5 = Wt[(size_t)j5 * H + h];
            float v6 = Wt[(size_t)j6 * H + h];
            float v7 = Wt[(size_t)j7 * H + h];
            cur2 += v0; cur2 += v1; cur2 += v2; cur2 += v3;
            cur2 += v4; cur2 += v5; cur2 += v6; cur2 += v7;
        }
        for (; i < n; ++i) cur2 += Wt[(size_t)il[i] * H + h];

        float hv = keep + cur2;
        bool sp = hv > 0.5f;
        keep = sp ? 0.0f : hv * 0.5f;
        u64 ball = __ballot(sp);
        if (lane == 0)
            hsbits[((size_t)b * T + t) * NW_H + wv] = ball;
    }
}

// ---------------- output currents: Iout[b*T+t][o] ----------------
__global__ void __launch_bounds__(256)
out_currents(const u64* __restrict__ hsbits,
             const float* __restrict__ WoT,
             float* __restrict__ Iout) {
    __shared__ int lidx[4][2][256];

    int wv   = threadIdx.x >> 6;
    int lane = threadIdx.x & 63;
    int row  = blockIdx.x * 4 + wv;   // < 64000 exactly

    const u64* wp = hsbits + (size_t)row * NW_H;

    float acc = 0.0f;
#pragma unroll
    for (int g = 0; g < 4; ++g) {
        u64 w[4];
#pragma unroll
        for (int k = 0; k < 4; ++k) w[k] = wp[g * 4 + k];

        int base[5];
        base[0] = 0;
#pragma unroll
        for (int k = 0; k < 4; ++k) base[k + 1] = base[k] + __popcll(w[k]);
        int n = base[4];

        int buf = g & 1;
#pragma unroll
        for (int k = 0; k < 4; ++k) {
            u64 m = w[k];
            if ((m >> lane) & 1ull) {
                int pos = base[k] + __popcll(m & ((1ull << lane) - 1ull));
                lidx[wv][buf][pos] = ((g * 4 + k) << 6) + lane;
            }
        }
        __syncthreads();

        const int* il = lidx[wv][buf];
        int i = 0;
        for (; i + 4 <= n; i += 4) {
            int j0 = il[i + 0], j1 = il[i + 1], j2 = il[i + 2], j3 = il[i + 3];
            if (lane < DOUT) {
                float v0 = WoT[(size_t)j0 * DOUT + lane];
                float v1 = WoT[(size_t)j1 * DOUT + lane];
                float v2 = WoT[(size_t)j2 * DOUT + lane];
                float v3 = WoT[(size_t)j3 * DOUT + lane];
                acc += v0; acc += v1; acc += v2; acc += v3;
            }
        }
        for (; i < n; ++i) {
            if (lane < DOUT) acc += WoT[(size_t)il[i] * DOUT + lane];
        }
    }
    if (lane < DOUT) Iout[(size_t)row * DOUT + lane] = acc;
}

// ---------------- output scan + spike count (LDS-staged) ----------------
// One block per b: stage the 250x20 Iout panel (20 KB) via coalesced loads,
// then lanes 0..19 run the recurrence from LDS. Identical arithmetic/order.
__global__ void __launch_bounds__(256)
out_scan(const float* __restrict__ Iout,
         const float* __restrict__ os0,
         const float* __restrict__ ov0,
         float* __restrict__ outp) {
    __shared__ float pan[T * DOUT];   // 20,000 B

    int b   = blockIdx.x;
    int tid = threadIdx.x;

    const float* src = Iout + (size_t)b * T * DOUT;
#pragma unroll
    for (int k = 0; k < 20; ++k) {
        int i = k * 256 + tid;
        if (i < T * DOUT) pan[i] = src[i];
    }
    __syncthreads();

    if (tid < DOUT) {
        int o = tid;
        int idx = b * DOUT + o;
        float ov = ov0[idx];
        float os = os0[idx];
        float keep = ov * 0.5f * (1.0f - os);
        float cnt = 0.0f;
#pragma unroll 5
        for (int t = 0; t < T; ++t) {
            float v = keep + pan[t * DOUT + o];
            float sp = (v > 0.5f) ? 1.0f : 0.0f;
            cnt += sp;
            keep = v * 0.5f * (1.0f - sp);
        }
        outp[idx] = cnt;
    }
}

extern "C" void kernel_launch(void* const* d_in, const int* in_sizes, int n_in,
                              void* d_out, int out_size, void* d_ws, size_t ws_size,
                              hipStream_t stream) {
    const float* spike = (const float*)d_in[0];   // [256][700][250]
    const float* W_hid = (const float*)d_in[1];   // [1024][700]
    const float* W_out = (const float*)d_in[2];   // [20][1024]
    const float* hs0   = (const float*)d_in[3];   // [256][1024]
    const float* hv0   = (const float*)d_in[4];
    const float* os0   = (const float*)d_in[5];   // [256][20]
    const float* ov0   = (const float*)d_in[6];
    float* outp = (float*)d_out;                  // [256][20]

    char* ws = (char*)d_ws;
    float*          Wt     = (float*)(ws);                      // 2,867,200 B
    float*          WoT    = (float*)(ws + 2867200);            //    81,920 B
    u64*            bits   = (u64*)  (ws + 2949120);            // 6,144,000 B
    u64*            hsbits = (u64*)  (ws + 9093120);            // 8,192,000 B
    float*          Iout   = (float*)(ws + 17285120);           // 5,120,000 B
    unsigned short* lists  = (unsigned short*)(ws + 22405120);  // 20,480,000 B
    unsigned short* nrow   = (unsigned short*)(ws + 42885120);  //   128,000 B
    const size_t need = 43013120;

    prep_weights<<<2880, 256, 0, stream>>>(W_hid, W_out, Wt, WoT);
    prep_bits<<<1024, 256, 0, stream>>>(spike, bits);

    if (ws_size >= need) {
        prep_lists<<<250, 256, 0, stream>>>(bits, lists, nrow);
        hidden_slice2<<<dim3(32, 256), 512, 0, stream>>>(lists, nrow, Wt, hs0, hv0, hsbits);
    } else {
        hidden_fused<<<B, 1024, 0, stream>>>(bits, Wt, hs0, hv0, hsbits);
    }

    out_currents<<<16000, 256, 0, stream>>>(hsbits, WoT, Iout);
    out_scan<<<B, 256, 0, stream>>>(Iout, os0, ov0, outp);
}

// Round 6
// 994.777 us; speedup vs baseline: 1.4839x; 1.0212x over previous
//
#include <hip/hip_runtime.h>
#include <stdint.h>

#define B      256
#define DIN    700
#define T      250
#define H      1024
#define DOUT   20
#define NW_IN  11     // u64 words for 700 input bits
#define NW_INP 12     // padded
#define NW_H   16     // u64 words for 1024 hidden bits
#define LMAX   160    // per-row list capacity (two padded sublists)
#define JSENT  44896  // sentinel pre-offset: local row 350 (zeros)

typedef unsigned long long u64;

// ---------------- prep: transpose weights ----------------
__global__ void prep_weights(const float* __restrict__ W_hid,
                             const float* __restrict__ W_out,
                             float* __restrict__ Wt,
                             float* __restrict__ WoT) {
    int idx = blockIdx.x * 256 + threadIdx.x;
    if (blockIdx.x < 2800) {
        int d = idx / H;
        int h = idx - d * H;
        Wt[idx] = W_hid[h * DIN + d];
    } else {
        int i = idx - 2800 * 256;   // 0..20479
        int h = i / DOUT;
        int o = i - h * DOUT;
        WoT[i] = W_out[o * H + h];
    }
}

// ---------------- prep: bitpack spikes ----------------
__global__ void prep_bits(const float* __restrict__ spk,
                          u64* __restrict__ bits) {
    int b  = blockIdx.x >> 2;
    int wc = blockIdx.x & 3;
    int t  = threadIdx.x;
    if (t >= T) return;
    int w0 = wc * 3;
    int w1 = (wc == 3) ? NW_IN : w0 + 3;
    const float* base = spk + (size_t)b * DIN * T + t;
    for (int w = w0; w < w1; ++w) {
        u64 m = 0;
#pragma unroll
        for (int j = 0; j < 64; ++j) {
            int d = (w << 6) + j;
            if (d < DIN) {
                float x = base[(size_t)d * T];
                m |= (u64)(x > 0.5f) << j;
            }
        }
        bits[((size_t)b * T + t) * NW_INP + w] = m;
    }
}

// ---------------- prep: wave-per-row list expansion (coalesced) ----------------
// One wave per (b,t) row. Parallel expansion: for each of the 11 words, lane l
// tests bit l and scatters its pre-swizzled LDS byte offset into LDS scratch at
// the prefix position (ascending j preserved). Sublist A: j<350, B: j>=350
// (local j-350), each padded to a multiple of 8 with JSENT. Coalesced u32
// copy-out. nrow packs the two chunk counts (u8 each).
__global__ void __launch_bounds__(256)
prep_lists2(const u64* __restrict__ bits,
            unsigned short* __restrict__ lists,
            unsigned short* __restrict__ nrow) {
    __shared__ unsigned short scr[4][LMAX];

    int wv   = threadIdx.x >> 6;
    int lane = threadIdx.x & 63;
    int row  = blockIdx.x * 4 + wv;   // 16000 blocks -> exactly 64000 rows

    const u64* wp = bits + (size_t)row * NW_INP;
    u64 mw = (lane < NW_IN) ? wp[lane] : 0ull;

    // pre-fill scratch with sentinels
    for (int i = lane; i < LMAX; i += 64) scr[wv][i] = (unsigned short)JSENT;

    u64 lowmask = (1ull << lane) - 1ull;

    // ---- sublist A: j in [0,350) ----
    int baseA = 0;
#pragma unroll
    for (int k = 0; k < 6; ++k) {
        u64 m = __shfl(mw, k);
        if (k == 5) m &= (1ull << 30) - 1ull;
        if ((m >> lane) & 1ull) {
            int pos = baseA + __popcll(m & lowmask);
            int j = (k << 6) + lane;
            if (pos < LMAX)
                scr[wv][pos] = (unsigned short)(j * 128 + ((j & 7) << 4));
        }
        baseA += __popcll(m);
    }
    int cA = (baseA + 7) >> 3;
    int bs = cA * 8;

    // ---- sublist B: j in [350,700), local jl = j-350 ----
    int baseB = 0;
#pragma unroll
    for (int k = 5; k < NW_IN; ++k) {
        u64 m = __shfl(mw, k);
        if (k == 5) m &= ~((1ull << 30) - 1ull);
        if ((m >> lane) & 1ull) {
            int pos = bs + baseB + __popcll(m & lowmask);
            int jl = (k << 6) + lane - 350;
            if (pos < LMAX)
                scr[wv][pos] = (unsigned short)(jl * 128 + ((jl & 7) << 4));
        }
        baseB += __popcll(m);
    }
    int cB = (baseB + 7) >> 3;

    if (lane == 0) nrow[row] = (unsigned short)(cA | (cB << 8));

    __syncthreads();

    // ---- coalesced copy-out: 160 u16 = 80 u32 ----
    const unsigned* s32 = (const unsigned*)scr[wv];
    unsigned* g32 = (unsigned*)(lists + (size_t)row * LMAX);
    g32[lane] = s32[lane];
    if (lane < 16) g32[64 + lane] = s32[64 + lane];
}

// ---------------- prep: per-b counting sort of rows by sublist count ----------
// permA/permB: for each b, rows 0..249 ordered by ascending cA / cB. Octets of
// the sorted order are count-homogeneous -> wave max-c ~= mean c (kills the
// sentinel-padding waste in the gather). Any permutation is correctness-safe:
// gather writes cur[r] per actual row r; scan runs after a barrier.
__global__ void __launch_bounds__(256)
sort_rows(const unsigned short* __restrict__ nrow,
          unsigned char* __restrict__ permA,
          unsigned char* __restrict__ permB) {
    __shared__ unsigned cntA[24], cntB[24], offA[24], offB[24];
    int b = blockIdx.x, tid = threadIdx.x;
    if (tid < 24) { cntA[tid] = 0; cntB[tid] = 0; }
    __syncthreads();
    int cA = 0, cB = 0;
    if (tid < T) {
        unsigned cc = nrow[b * T + tid];
        cA = cc & 0xff;          if (cA > 23) cA = 23;
        cB = (cc >> 8) & 0xff;   if (cB > 23) cB = 23;
        atomicAdd(&cntA[cA], 1);
        atomicAdd(&cntB[cB], 1);
    }
    __syncthreads();
    if (tid == 0) { unsigned s = 0; for (int i = 0; i < 24; ++i) { offA[i] = s; s += cntA[i]; cntA[i] = 0; } }
    if (tid == 1) { unsigned s = 0; for (int i = 0; i < 24; ++i) { offB[i] = s; s += cntB[i]; cntB[i] = 0; } }
    __syncthreads();
    if (tid < T) {
        unsigned pA = offA[cA] + atomicAdd(&cntA[cA], 1);
        unsigned pB = offB[cB] + atomicAdd(&cntB[cB], 1);
        permA[b * 256 + pA] = (unsigned char)tid;
        permB[b * 256 + pB] = (unsigned char)tid;
    }
}

// ---------------- hidden layer: swizzled LDS Wt slice, 2 j-passes, fused scan ----
// Block = (32-h slice s, batch b), 512 threads, 77 KB LDS -> 2 blocks/CU =
// 4 waves/SIMD. 64 8-lane groups gather one t-row each per sweep; rows are
// assigned via the count-sorted permutation so each octet is count-homogeneous.
// Pass B continues pass A's running sum (sequential ascending-j fp32 chain per
// h -> bit-exact). Fused scan writes u32 halves of hsbits (plain layout).
__global__ void __launch_bounds__(512, 2)
hidden_slice2(const unsigned short* __restrict__ lists,
              const unsigned short* __restrict__ nrow,
              const unsigned char* __restrict__ permA,
              const unsigned char* __restrict__ permB,
              const float* __restrict__ Wt,
              const float* __restrict__ hs0,
              const float* __restrict__ hv0,
              u64* __restrict__ hsbits) {
    __shared__ float wlds[351 * 32];   // 44,928 B (row 350 = zeros)
    __shared__ float cur[250 * 32];    // 32,000 B

    int s    = blockIdx.x;        // 0..31 h-slice
    int b    = blockIdx.y;        // 0..255
    int tid  = threadIdx.x;
    int wv   = tid >> 6;
    int lane = tid & 63;
    int g    = lane >> 3;
    int li   = lane & 7;
    int lxor = li << 4;

    for (int p = 0; p < 2; ++p) {
        // ---- stage half-Wt slice, swizzled: slot = li ^ (j&7) ----
        {
            int jr  = tid >> 3;                // 0..63
            int lis = tid & 7;
#pragma unroll
            for (int base_j = 0; base_j < 384; base_j += 64) {
                int j = base_j + jr;
                if (j < 351) {
                    float4 v;
                    if (j < 350)
                        v = *(const float4*)(Wt + (size_t)(p * 350 + j) * H + s * 32 + lis * 4);
                    else
                        v = make_float4(0.0f, 0.0f, 0.0f, 0.0f);
                    *(float4*)((char*)wlds + j * 128 + ((lis ^ (j & 7)) << 4)) = v;
                }
            }
        }
        __syncthreads();

        const unsigned char* pm = (p ? permB : permA) + b * 256;

        // ---- gather: 250 rows, 64 per sweep (8 waves x 8 groups) ----
        for (int sweep = 0; sweep < 4; ++sweep) {
            int rr = sweep * 64 + wv * 8 + g;   // sorted slot
            if (rr < 250) {
                int r   = pm[rr];               // actual t
                int row = b * T + r;
                unsigned cc = nrow[row];
                int cA = cc & 0xff;
                int c  = p ? ((cc >> 8) & 0xff) : cA;
                const uint4* qp = (const uint4*)(lists + (size_t)row * LMAX + (p ? cA * 8 : 0));

                float a0, a1, a2, a3;
                if (p == 0) {
                    a0 = a1 = a2 = a3 = 0.0f;
                } else {
                    float4 cv = *(const float4*)((char*)cur + r * 128 + lxor);
                    a0 = cv.x; a1 = cv.y; a2 = cv.z; a3 = cv.w;
                }

                if (c > 0) {
                    uint4 w4 = qp[0];
                    int ch = 0;
                    for (;;) {
                        uint4 nw = (ch + 1 < c) ? qp[ch + 1] : w4;
                        int e0 = w4.x & 0xffff, e1 = w4.x >> 16;
                        int e2 = w4.y & 0xffff, e3 = w4.y >> 16;
                        int e4 = w4.z & 0xffff, e5 = w4.z >> 16;
                        int e6 = w4.w & 0xffff, e7 = w4.w >> 16;
                        float4 v0 = *(const float4*)((char*)wlds + (e0 ^ lxor));
                        float4 v1 = *(const float4*)((char*)wlds + (e1 ^ lxor));
                        float4 v2 = *(const float4*)((char*)wlds + (e2 ^ lxor));
                        float4 v3 = *(const float4*)((char*)wlds + (e3 ^ lxor));
                        float4 v4 = *(const float4*)((char*)wlds + (e4 ^ lxor));
                        float4 v5 = *(const float4*)((char*)wlds + (e5 ^ lxor));
                        float4 v6 = *(const float4*)((char*)wlds + (e6 ^ lxor));
                        float4 v7 = *(const float4*)((char*)wlds + (e7 ^ lxor));
                        a0 += v0.x; a1 += v0.y; a2 += v0.z; a3 += v0.w;
                        a0 += v1.x; a1 += v1.y; a2 += v1.z; a3 += v1.w;
                        a0 += v2.x; a1 += v2.y; a2 += v2.z; a3 += v2.w;
                        a0 += v3.x; a1 += v3.y; a2 += v3.z; a3 += v3.w;
                        a0 += v4.x; a1 += v4.y; a2 += v4.z; a3 += v4.w;
                        a0 += v5.x; a1 += v5.y; a2 += v5.z; a3 += v5.w;
                        a0 += v6.x; a1 += v6.y; a2 += v6.z; a3 += v6.w;
                        a0 += v7.x; a1 += v7.y; a2 += v7.z; a3 += v7.w;
                        ++ch;
                        if (ch >= c) break;
                        w4 = nw;
                    }
                }
                float4 o; o.x = a0; o.y = a1; o.z = a2; o.w = a3;
                *(float4*)((char*)cur + r * 128 + lxor) = o;
            }
        }
        __syncthreads();
    }

    // ---- fused scan: wave 0 (lanes 32-63 mirror), 32 h of this (s,b) ----
    if (wv == 0) {
        int l = lane & 31;
        int h = s * 32 + l;
        float keep = hv0[b * H + h] * 0.5f * (1.0f - hs0[b * H + h]);
        unsigned* hp = (unsigned*)hsbits;
        float c = cur[l];
        for (int t = 0; t < T; ++t) {
            float cn = (t + 1 < T) ? cur[(t + 1) * 32 + l] : 0.0f;
            float hv = keep + c;
            bool sp = hv > 0.5f;
            keep = sp ? 0.0f : hv * 0.5f;
            u64 ball = __ballot(sp);
            if (lane == 0)
                hp[(size_t)(b * T + t) * 32 + s] = (unsigned)ball;
            c = cn;
        }
    }
}

// ---------------- fallback: round-0 fused hidden kernel (proven) ----------------
__global__ void __launch_bounds__(1024)
hidden_fused(const u64* __restrict__ bits,
             const float* __restrict__ Wt,
             const float* __restrict__ hs0,
             const float* __restrict__ hv0,
             u64* __restrict__ hsbits) {
    __shared__ int idx_l[2][256];

    int b = blockIdx.x;
    int h = threadIdx.x;
    int wv   = h >> 6;
    int lane = h & 63;

    float keep = hv0[b * H + h] * 0.5f * (1.0f - hs0[b * H + h]);

    const u64* bb = bits + (size_t)b * T * NW_INP;

    for (int t = 0; t < T; ++t) {
        const u64* wp = bb + (size_t)t * NW_INP;
        u64 w[NW_IN];
#pragma unroll
        for (int k = 0; k < NW_IN; ++k) w[k] = wp[k];

        int base[NW_IN + 1];
        base[0] = 0;
#pragma unroll
        for (int k = 0; k < NW_IN; ++k) base[k + 1] = base[k] + __popcll(w[k]);
        int n = base[NW_IN];

        int buf = t & 1;
        if (wv < NW_IN) {
            u64 m = w[wv];
            if ((m >> lane) & 1ull) {
                int pos = base[wv] + __popcll(m & ((1ull << lane) - 1ull));
                idx_l[buf][pos] = (wv << 6) + lane;
            }
        }
        __syncthreads();

        const int* il = idx_l[buf];
        float cur2 = 0.0f;
        int i = 0;
        for (; i + 8 <= n; i += 8) {
            int j0 = il[i + 0], j1 = il[i + 1], j2 = il[i + 2], j3 = il[i + 3];
            int j4 = il[i + 4], j5 = il[i + 5], j6 = il[i + 6], j7 = il[i + 7];
            float v0 = Wt[(size_t)j0 * H + h];
            float v1 = Wt[(size_t)j1 * H + h];
            float v2 = Wt[(size_t)j2 * H + h];
            float v3 = Wt[(size_t)j3 * H + h];
            float v4 = Wt[(size_t)j4 * H + h];
            float v5 = Wt[(size_t)j5 * H + h];
            float v6 = Wt[(size_t)j6 * H + h];
            float v7 = Wt[(size_t)j7 * H + h];
            cur2 += v0; cur2 += v1; cur2 += v2; cur2 += v3;
            cur2 += v4; cur2 += v5; cur2 += v6; cur2 += v7;
        }
        for (; i < n; ++i) cur2 += Wt[(size_t)il[i] * H + h];

        float hv = keep + cur2;
        bool sp = hv > 0.5f;
        keep = sp ? 0.0f : hv * 0.5f;
        u64 ball = __ballot(sp);
        if (lane == 0)
            hsbits[((size_t)b * T + t) * NW_H + wv] = ball;
    }
}

// ---------------- output currents: Iout[b*T+t][o] ----------------
__global__ void __launch_bounds__(256)
out_currents(const u64* __restrict__ hsbits,
             const float* __restrict__ WoT,
             float* __restrict__ Iout) {
    __shared__ int lidx[4][2][256];

    int wv   = threadIdx.x >> 6;
    int lane = threadIdx.x & 63;
    int row  = blockIdx.x * 4 + wv;   // < 64000 exactly

    const u64* wp = hsbits + (size_t)row * NW_H;

    float acc = 0.0f;
#pragma unroll
    for (int g = 0; g < 4; ++g) {
        u64 w[4];
#pragma unroll
        for (int k = 0; k < 4; ++k) w[k] = wp[g * 4 + k];

        int base[5];
        base[0] = 0;
#pragma unroll
        for (int k = 0; k < 4; ++k) base[k + 1] = base[k] + __popcll(w[k]);
        int n = base[4];

        int buf = g & 1;
#pragma unroll
        for (int k = 0; k < 4; ++k) {
            u64 m = w[k];
            if ((m >> lane) & 1ull) {
                int pos = base[k] + __popcll(m & ((1ull << lane) - 1ull));
                lidx[wv][buf][pos] = ((g * 4 + k) << 6) + lane;
            }
        }
        __syncthreads();

        const int* il = lidx[wv][buf];
        int i = 0;
        for (; i + 4 <= n; i += 4) {
            int j0 = il[i + 0], j1 = il[i + 1], j2 = il[i + 2], j3 = il[i + 3];
            if (lane < DOUT) {
                float v0 = WoT[(size_t)j0 * DOUT + lane];
                float v1 = WoT[(size_t)j1 * DOUT + lane];
                float v2 = WoT[(size_t)j2 * DOUT + lane];
                float v3 = WoT[(size_t)j3 * DOUT + lane];
                acc += v0; acc += v1; acc += v2; acc += v3;
            }
        }
        for (; i < n; ++i) {
            if (lane < DOUT) acc += WoT[(size_t)il[i] * DOUT + lane];
        }
    }
    if (lane < DOUT) Iout[(size_t)row * DOUT + lane] = acc;
}

// ---------------- output scan + spike count (LDS-staged) ----------------
__global__ void __launch_bounds__(256)
out_scan(const float* __restrict__ Iout,
         const float* __restrict__ os0,
         const float* __restrict__ ov0,
         float* __restrict__ outp) {
    __shared__ float pan[T * DOUT];   // 20,000 B

    int b   = blockIdx.x;
    int tid = threadIdx.x;

    const float* src = Iout + (size_t)b * T * DOUT;
#pragma unroll
    for (int k = 0; k < 20; ++k) {
        int i = k * 256 + tid;
        if (i < T * DOUT) pan[i] = src[i];
    }
    __syncthreads();

    if (tid < DOUT) {
        int o = tid;
        int idx = b * DOUT + o;
        float ov = ov0[idx];
        float os = os0[idx];
        float keep = ov * 0.5f * (1.0f - os);
        float cnt = 0.0f;
#pragma unroll 5
        for (int t = 0; t < T; ++t) {
            float v = keep + pan[t * DOUT + o];
            float sp = (v > 0.5f) ? 1.0f : 0.0f;
            cnt += sp;
            keep = v * 0.5f * (1.0f - sp);
        }
        outp[idx] = cnt;
    }
}

extern "C" void kernel_launch(void* const* d_in, const int* in_sizes, int n_in,
                              void* d_out, int out_size, void* d_ws, size_t ws_size,
                              hipStream_t stream) {
    const float* spike = (const float*)d_in[0];   // [256][700][250]
    const float* W_hid = (const float*)d_in[1];   // [1024][700]
    const float* W_out = (const float*)d_in[2];   // [20][1024]
    const float* hs0   = (const float*)d_in[3];   // [256][1024]
    const float* hv0   = (const float*)d_in[4];
    const float* os0   = (const float*)d_in[5];   // [256][20]
    const float* ov0   = (const float*)d_in[6];
    float* outp = (float*)d_out;                  // [256][20]

    char* ws = (char*)d_ws;
    float*          Wt     = (float*)(ws);                      // 2,867,200 B
    float*          WoT    = (float*)(ws + 2867200);            //    81,920 B
    u64*            bits   = (u64*)  (ws + 2949120);            // 6,144,000 B
    u64*            hsbits = (u64*)  (ws + 9093120);            // 8,192,000 B
    float*          Iout   = (float*)(ws + 17285120);           // 5,120,000 B
    unsigned short* lists  = (unsigned short*)(ws + 22405120);  // 20,480,000 B
    unsigned short* nrow   = (unsigned short*)(ws + 42885120);  //   128,000 B
    unsigned char*  permA  = (unsigned char*)(ws + 43013120);   //    65,536 B
    unsigned char*  permB  = (unsigned char*)(ws + 43078656);   //    65,536 B
    const size_t need = 43144192;

    prep_weights<<<2880, 256, 0, stream>>>(W_hid, W_out, Wt, WoT);
    prep_bits<<<1024, 256, 0, stream>>>(spike, bits);

    if (ws_size >= need) {
        prep_lists2<<<16000, 256, 0, stream>>>(bits, lists, nrow);
        sort_rows<<<B, 256, 0, stream>>>(nrow, permA, permB);
        hidden_slice2<<<dim3(32, 256), 512, 0, stream>>>(lists, nrow, permA, permB, Wt, hs0, hv0, hsbits);
    } else {
        hidden_fused<<<B, 1024, 0, stream>>>(bits, Wt, hs0, hv0, hsbits);
    }

    out_currents<<<16000, 256, 0, stream>>>(hsbits, WoT, Iout);
    out_scan<<<B, 256, 0, stream>>>(Iout, os0, ov0, outp);
}

// Round 7
// 987.989 us; speedup vs baseline: 1.4941x; 1.0069x over previous
//
#include <hip/hip_runtime.h>
#include <stdint.h>

#define B      256
#define DIN    700
#define T      250
#define H      1024
#define DOUT   20
#define NW_IN  11     // u64 words for 700 input bits
#define NW_INP 12     // padded
#define NW_H   16     // u64 words for 1024 hidden bits
#define LMAX   160    // per-row list capacity (4 packed sublists, chunk-4 padded)
#define JSENT2 22512  // sentinel pre-offset: local row 175 (zeros)

typedef unsigned long long u64;

// ---------------- prep: transpose weights ----------------
__global__ void prep_weights(const float* __restrict__ W_hid,
                             const float* __restrict__ W_out,
                             float* __restrict__ Wt,
                             float* __restrict__ WoT) {
    int idx = blockIdx.x * 256 + threadIdx.x;
    if (blockIdx.x < 2800) {
        int d = idx / H;
        int h = idx - d * H;
        Wt[idx] = W_hid[h * DIN + d];
    } else {
        int i = idx - 2800 * 256;   // 0..20479
        int h = i / DOUT;
        int o = i - h * DOUT;
        WoT[i] = W_out[o * H + h];
    }
}

// ---------------- prep: bitpack spikes ----------------
__global__ void prep_bits(const float* __restrict__ spk,
                          u64* __restrict__ bits) {
    int b  = blockIdx.x >> 2;
    int wc = blockIdx.x & 3;
    int t  = threadIdx.x;
    if (t >= T) return;
    int w0 = wc * 3;
    int w1 = (wc == 3) ? NW_IN : w0 + 3;
    const float* base = spk + (size_t)b * DIN * T + t;
    for (int w = w0; w < w1; ++w) {
        u64 m = 0;
#pragma unroll
        for (int j = 0; j < 64; ++j) {
            int d = (w << 6) + j;
            if (d < DIN) {
                float x = base[(size_t)d * T];
                m |= (u64)(x > 0.5f) << j;
            }
        }
        bits[((size_t)b * T + t) * NW_INP + w] = m;
    }
}

// ---------------- prep: 4 packed sublists of pre-swizzled LDS byte offsets ----
// Sublist p: j in [175p, 175p+175), local jl = j-175p. Entry = jl*128 +
// ((jl&7)<<4); lane address = entry ^ (li<<4). Each sublist padded to a
// multiple of 4 with JSENT2 (zero row 175). nrow packs 4 chunk counts (u8).
__global__ void __launch_bounds__(256)
prep_lists2(const u64* __restrict__ bits,
            unsigned short* __restrict__ lists,
            unsigned* __restrict__ nrow) {
    __shared__ unsigned short scr[4][LMAX];

    int wv   = threadIdx.x >> 6;
    int lane = threadIdx.x & 63;
    int row  = blockIdx.x * 4 + wv;   // 16000 blocks -> exactly 64000 rows

    const u64* wp = bits + (size_t)row * NW_INP;
    u64 mw = (lane < NW_IN) ? wp[lane] : 0ull;

    for (int i = lane; i < LMAX; i += 64) scr[wv][i] = (unsigned short)JSENT2;

    u64 lowmask = (1ull << lane) - 1ull;
    int pos = 0;
    unsigned counts = 0;

#pragma unroll
    for (int p = 0; p < 4; ++p) {
        int jlo = 175 * p, jhi = jlo + 175;
        int n = 0;
        for (int k = jlo >> 6; k <= (jhi - 1) >> 6; ++k) {
            u64 m = __shfl(mw, k);
            int lo = jlo - (k << 6);
            int hi = jhi - (k << 6);
            if (lo > 0)  m &= ~((1ull << lo) - 1ull);
            if (hi < 64) m &= (1ull << hi) - 1ull;
            if ((m >> lane) & 1ull) {
                int q = pos + n + __popcll(m & lowmask);
                int jl = (k << 6) + lane - jlo;
                if (q < LMAX)
                    scr[wv][q] = (unsigned short)(jl * 128 + ((jl & 7) << 4));
            }
            n += __popcll(m);
        }
        int c = (n + 3) >> 2;           // chunks of 4
        counts |= (unsigned)c << (8 * p);
        pos += c * 4;
    }

    if (lane == 0) nrow[row] = counts;
    __syncthreads();

    const unsigned* s32 = (const unsigned*)scr[wv];
    unsigned* g32 = (unsigned*)(lists + (size_t)row * LMAX);
    g32[lane] = s32[lane];
    if (lane < 16) g32[64 + lane] = s32[64 + lane];
}

// ---------------- prep: counting sort per (b, sublist, t-half) ----------------
// perm[(b*8 + p*2 + half)*128 + rank] = local row (0..124), ascending chunk
// count. Octets become count-homogeneous -> wave max-c ~= mean c. Any
// permutation is correctness-safe (gather writes cur[lr]; scan after barrier).
__global__ void __launch_bounds__(256)
sort_rows(const unsigned* __restrict__ nrow,
          unsigned char* __restrict__ perm) {
    __shared__ int cnt[8][32];
    __shared__ int off[8][32];
    int b = blockIdx.x, tid = threadIdx.x;
    cnt[tid >> 5][tid & 31] = 0;
    __syncthreads();
    unsigned cc = 0; int half = 0, lt = 0;
    if (tid < T) {
        cc = nrow[b * T + tid];
        half = tid >= 125;
        lt = tid - half * 125;
#pragma unroll
        for (int p = 0; p < 4; ++p) {
            int c = (cc >> (8 * p)) & 0xff; if (c > 31) c = 31;
            atomicAdd(&cnt[p * 2 + half][c], 1);
        }
    }
    __syncthreads();
    if (tid < 8) {
        int s = 0;
        for (int i = 0; i < 32; ++i) { off[tid][i] = s; s += cnt[tid][i]; cnt[tid][i] = 0; }
    }
    __syncthreads();
    if (tid < T) {
#pragma unroll
        for (int p = 0; p < 4; ++p) {
            int c = (cc >> (8 * p)) & 0xff; if (c > 31) c = 31;
            int sidx = p * 2 + half;
            int rank = off[sidx][c] + atomicAdd(&cnt[sidx][c], 1);
            perm[((size_t)b * 8 + sidx) * 128 + rank] = (unsigned char)lt;
        }
    }
}

// ---------------- hidden layer: 38.5 KB LDS -> 4 blocks/CU (32 waves/CU) ----
// Block = (32-h slice s, batch b), 512 threads. j in 4 staged passes (176-row
// swizzled slice), t in 2 halves (cur = 125x32, row-swizzled). Pass p>0
// continues the carried partial sum -> per-(t,h) one sequential ascending-j
// fp32 chain (bit-exact). Scan per half in wave 0, keep carried in registers.
__global__ void __launch_bounds__(512, 8)
hidden_slice3(const unsigned short* __restrict__ lists,
              const unsigned* __restrict__ nrow,
              const unsigned char* __restrict__ perm,
              const float* __restrict__ Wt,
              const float* __restrict__ hs0,
              const float* __restrict__ hv0,
              u64* __restrict__ hsbits) {
    __shared__ float wlds[176 * 32];   // 22,528 B (row 175 = zeros)
    __shared__ float cur[125 * 32];    // 16,000 B

    int s    = blockIdx.x;        // 0..31 h-slice
    int b    = blockIdx.y;        // 0..255
    int tid  = threadIdx.x;
    int wv   = tid >> 6;
    int lane = tid & 63;
    int g    = lane >> 3;
    int li   = lane & 7;
    int lxor = li << 4;
    int l    = lane & 31;

    float keep = 0.0f;
    if (wv == 0) {
        int h = s * 32 + l;
        keep = hv0[b * H + h] * 0.5f * (1.0f - hs0[b * H + h]);
    }
    unsigned* hp = (unsigned*)hsbits;

    for (int th = 0; th < 2; ++th) {
        for (int p = 0; p < 4; ++p) {
            // ---- stage quarter-Wt slice, swizzled: slot = lis ^ (jl&7) ----
            {
                int jr  = tid >> 3;            // 0..63
                int lis = tid & 7;
#pragma unroll
                for (int bj = 0; bj < 192; bj += 64) {
                    int jl = bj + jr;
                    if (jl < 176) {
                        float4 v = make_float4(0.0f, 0.0f, 0.0f, 0.0f);
                        if (jl < 175)
                            v = *(const float4*)(Wt + (size_t)(p * 175 + jl) * H + s * 32 + lis * 4);
                        *(float4*)((char*)wlds + jl * 128 + ((lis ^ (jl & 7)) << 4)) = v;
                    }
                }
            }
            __syncthreads();

            const unsigned char* pm = perm + ((size_t)b * 8 + p * 2 + th) * 128;

            // ---- gather: 125 rows, 64 groups -> 2 sweeps ----
#pragma unroll
            for (int sweep = 0; sweep < 2; ++sweep) {
                int rr = sweep * 64 + wv * 8 + g;
                if (rr < 125) {
                    int lr  = pm[rr];
                    int r   = th * 125 + lr;
                    int row = b * T + r;
                    unsigned cc = nrow[row];
                    int c = (cc >> (8 * p)) & 0xff;
                    int offc = 0;
                    if (p > 0) offc += (cc & 0xff);
                    if (p > 1) offc += ((cc >> 8) & 0xff);
                    if (p > 2) offc += ((cc >> 16) & 0xff);
                    const uint2* qp = (const uint2*)(lists + (size_t)row * LMAX + offc * 4);
                    char* cp = (char*)cur + lr * 128 + ((li ^ (lr & 7)) << 4);

                    float a0, a1, a2, a3;
                    if (p == 0) {
                        a0 = a1 = a2 = a3 = 0.0f;
                    } else {
                        float4 cv = *(const float4*)cp;
                        a0 = cv.x; a1 = cv.y; a2 = cv.z; a3 = cv.w;
                    }

                    if (c > 0) {
                        uint2 w2 = qp[0];
                        int ch = 0;
                        for (;;) {
                            uint2 nw = (ch + 1 < c) ? qp[ch + 1] : w2;
                            int e0 = w2.x & 0xffff, e1 = w2.x >> 16;
                            int e2 = w2.y & 0xffff, e3 = w2.y >> 16;
                            float4 v0 = *(const float4*)((char*)wlds + (e0 ^ lxor));
                            float4 v1 = *(const float4*)((char*)wlds + (e1 ^ lxor));
                            float4 v2 = *(const float4*)((char*)wlds + (e2 ^ lxor));
                            float4 v3 = *(const float4*)((char*)wlds + (e3 ^ lxor));
                            a0 += v0.x; a1 += v0.y; a2 += v0.z; a3 += v0.w;
                            a0 += v1.x; a1 += v1.y; a2 += v1.z; a3 += v1.w;
                            a0 += v2.x; a1 += v2.y; a2 += v2.z; a3 += v2.w;
                            a0 += v3.x; a1 += v3.y; a2 += v3.z; a3 += v3.w;
                            ++ch;
                            if (ch >= c) break;
                            w2 = nw;
                        }
                    }
                    float4 o; o.x = a0; o.y = a1; o.z = a2; o.w = a3;
                    *(float4*)cp = o;
                }
            }
            __syncthreads();
        }

        // ---- scan this t-half: wave 0 (lanes 32-63 mirror), 32 h ----
        if (wv == 0) {
            for (int lt = 0; lt < 125; ++lt) {
                float cv = *(const float*)((char*)cur + lt * 128 +
                                           (((l >> 2) ^ (lt & 7)) << 4) + (l & 3) * 4);
                float hv = keep + cv;
                bool sp = hv > 0.5f;
                keep = sp ? 0.0f : hv * 0.5f;
                u64 ball = __ballot(sp);
                int t = th * 125 + lt;
                if (lane == 0)
                    hp[(size_t)(b * T + t) * 32 + s] = (unsigned)ball;
            }
        }
        __syncthreads();   // protect cur before next half overwrites
    }
}

// ---------------- fallback: round-0 fused hidden kernel (proven) ----------------
__global__ void __launch_bounds__(1024)
hidden_fused(const u64* __restrict__ bits,
             const float* __restrict__ Wt,
             const float* __restrict__ hs0,
             const float* __restrict__ hv0,
             u64* __restrict__ hsbits) {
    __shared__ int idx_l[2][256];

    int b = blockIdx.x;
    int h = threadIdx.x;
    int wv   = h >> 6;
    int lane = h & 63;

    float keep = hv0[b * H + h] * 0.5f * (1.0f - hs0[b * H + h]);

    const u64* bb = bits + (size_t)b * T * NW_INP;

    for (int t = 0; t < T; ++t) {
        const u64* wp = bb + (size_t)t * NW_INP;
        u64 w[NW_IN];
#pragma unroll
        for (int k = 0; k < NW_IN; ++k) w[k] = wp[k];

        int base[NW_IN + 1];
        base[0] = 0;
#pragma unroll
        for (int k = 0; k < NW_IN; ++k) base[k + 1] = base[k] + __popcll(w[k]);
        int n = base[NW_IN];

        int buf = t & 1;
        if (wv < NW_IN) {
            u64 m = w[wv];
            if ((m >> lane) & 1ull) {
                int pos = base[wv] + __popcll(m & ((1ull << lane) - 1ull));
                idx_l[buf][pos] = (wv << 6) + lane;
            }
        }
        __syncthreads();

        const int* il = idx_l[buf];
        float cur2 = 0.0f;
        int i = 0;
        for (; i + 8 <= n; i += 8) {
            int j0 = il[i + 0], j1 = il[i + 1], j2 = il[i + 2], j3 = il[i + 3];
            int j4 = il[i + 4], j5 = il[i + 5], j6 = il[i + 6], j7 = il[i + 7];
            float v0 = Wt[(size_t)j0 * H + h];
            float v1 = Wt[(size_t)j1 * H + h];
            float v2 = Wt[(size_t)j2 * H + h];
            float v3 = Wt[(size_t)j3 * H + h];
            float v4 = Wt[(size_t)j4 * H + h];
            float v5 = Wt[(size_t)j5 * H + h];
            float v6 = Wt[(size_t)j6 * H + h];
            float v7 = Wt[(size_t)j7 * H + h];
            cur2 += v0; cur2 += v1; cur2 += v2; cur2 += v3;
            cur2 += v4; cur2 += v5; cur2 += v6; cur2 += v7;
        }
        for (; i < n; ++i) cur2 += Wt[(size_t)il[i] * H + h];

        float hv = keep + cur2;
        bool sp = hv > 0.5f;
        keep = sp ? 0.0f : hv * 0.5f;
        u64 ball = __ballot(sp);
        if (lane == 0)
            hsbits[((size_t)b * T + t) * NW_H + wv] = ball;
    }
}

// ---------------- output currents: Iout[b*T+t][o] ----------------
__global__ void __launch_bounds__(256)
out_currents(const u64* __restrict__ hsbits,
             const float* __restrict__ WoT,
             float* __restrict__ Iout) {
    __shared__ int lidx[4][2][256];

    int wv   = threadIdx.x >> 6;
    int lane = threadIdx.x & 63;
    int row  = blockIdx.x * 4 + wv;   // < 64000 exactly

    const u64* wp = hsbits + (size_t)row * NW_H;

    float acc = 0.0f;
#pragma unroll
    for (int g = 0; g < 4; ++g) {
        u64 w[4];
#pragma unroll
        for (int k = 0; k < 4; ++k) w[k] = wp[g * 4 + k];

        int base[5];
        base[0] = 0;
#pragma unroll
        for (int k = 0; k < 4; ++k) base[k + 1] = base[k] + __popcll(w[k]);
        int n = base[4];

        int buf = g & 1;
#pragma unroll
        for (int k = 0; k < 4; ++k) {
            u64 m = w[k];
            if ((m >> lane) & 1ull) {
                int pos = base[k] + __popcll(m & ((1ull << lane) - 1ull));
                lidx[wv][buf][pos] = ((g * 4 + k) << 6) + lane;
            }
        }
        __syncthreads();

        const int* il = lidx[wv][buf];
        int i = 0;
        for (; i + 4 <= n; i += 4) {
            int j0 = il[i + 0], j1 = il[i + 1], j2 = il[i + 2], j3 = il[i + 3];
            if (lane < DOUT) {
                float v0 = WoT[(size_t)j0 * DOUT + lane];
                float v1 = WoT[(size_t)j1 * DOUT + lane];
                float v2 = WoT[(size_t)j2 * DOUT + lane];
                float v3 = WoT[(size_t)j3 * DOUT + lane];
                acc += v0; acc += v1; acc += v2; acc += v3;
            }
        }
        for (; i < n; ++i) {
            if (lane < DOUT) acc += WoT[(size_t)il[i] * DOUT + lane];
        }
    }
    if (lane < DOUT) Iout[(size_t)row * DOUT + lane] = acc;
}

// ---------------- output scan + spike count (LDS-staged) ----------------
__global__ void __launch_bounds__(256)
out_scan(const float* __restrict__ Iout,
         const float* __restrict__ os0,
         const float* __restrict__ ov0,
         float* __restrict__ outp) {
    __shared__ float pan[T * DOUT];   // 20,000 B

    int b   = blockIdx.x;
    int tid = threadIdx.x;

    const float* src = Iout + (size_t)b * T * DOUT;
#pragma unroll
    for (int k = 0; k < 20; ++k) {
        int i = k * 256 + tid;
        if (i < T * DOUT) pan[i] = src[i];
    }
    __syncthreads();

    if (tid < DOUT) {
        int o = tid;
        int idx = b * DOUT + o;
        float ov = ov0[idx];
        float os = os0[idx];
        float keep = ov * 0.5f * (1.0f - os);
        float cnt = 0.0f;
#pragma unroll 5
        for (int t = 0; t < T; ++t) {
            float v = keep + pan[t * DOUT + o];
            float sp = (v > 0.5f) ? 1.0f : 0.0f;
            cnt += sp;
            keep = v * 0.5f * (1.0f - sp);
        }
        outp[idx] = cnt;
    }
}

extern "C" void kernel_launch(void* const* d_in, const int* in_sizes, int n_in,
                              void* d_out, int out_size, void* d_ws, size_t ws_size,
                              hipStream_t stream) {
    const float* spike = (const float*)d_in[0];   // [256][700][250]
    const float* W_hid = (const float*)d_in[1];   // [1024][700]
    const float* W_out = (const float*)d_in[2];   // [20][1024]
    const float* hs0   = (const float*)d_in[3];   // [256][1024]
    const float* hv0   = (const float*)d_in[4];
    const float* os0   = (const float*)d_in[5];   // [256][20]
    const float* ov0   = (const float*)d_in[6];
    float* outp = (float*)d_out;                  // [256][20]

    char* ws = (char*)d_ws;
    float*          Wt     = (float*)(ws);                      // 2,867,200 B
    float*          WoT    = (float*)(ws + 2867200);            //    81,920 B
    u64*            bits   = (u64*)  (ws + 2949120);            // 6,144,000 B
    u64*            hsbits = (u64*)  (ws + 9093120);            // 8,192,000 B
    float*          Iout   = (float*)(ws + 17285120);           // 5,120,000 B
    unsigned short* lists  = (unsigned short*)(ws + 22405120);  // 20,480,000 B
    unsigned*       nrow   = (unsigned*)(ws + 42885120);        //   256,000 B
    unsigned char*  perm   = (unsigned char*)(ws + 43141120);   //   262,144 B
    const size_t need = 43403264;

    prep_weights<<<2880, 256, 0, stream>>>(W_hid, W_out, Wt, WoT);
    prep_bits<<<1024, 256, 0, stream>>>(spike, bits);

    if (ws_size >= need) {
        prep_lists2<<<16000, 256, 0, stream>>>(bits, lists, nrow);
        sort_rows<<<B, 256, 0, stream>>>(nrow, perm);
        hidden_slice3<<<dim3(32, 256), 512, 0, stream>>>(lists, nrow, perm, Wt, hs0, hv0, hsbits);
    } else {
        hidden_fused<<<B, 1024, 0, stream>>>(bits, Wt, hs0, hv0, hsbits);
    }

    out_currents<<<16000, 256, 0, stream>>>(hsbits, WoT, Iout);
    out_scan<<<B, 256, 0, stream>>>(Iout, os0, ov0, outp);
}

// Round 8
// 965.400 us; speedup vs baseline: 1.5291x; 1.0234x over previous
//
#include <hip/hip_runtime.h>
#include <stdint.h>

#define B      256
#define DIN    700
#define T      250
#define H      1024
#define DOUT   20
#define NW_IN  11     // u64 words for 700 input bits
#define NW_INP 12     // padded
#define NW_H   16     // u64 words for 1024 hidden bits
#define LMAX   160    // per-row list capacity (4 packed sublists, chunk-4 padded)
#define JSENT2 22512  // sentinel pre-offset: local row 175 (zeros)

typedef unsigned long long u64;

// ---------------- prep: transpose weights ----------------
__global__ void prep_weights(const float* __restrict__ W_hid,
                             const float* __restrict__ W_out,
                             float* __restrict__ Wt,
                             float* __restrict__ WoT) {
    int idx = blockIdx.x * 256 + threadIdx.x;
    if (blockIdx.x < 2800) {
        int d = idx / H;
        int h = idx - d * H;
        Wt[idx] = W_hid[h * DIN + d];
    } else {
        int i = idx - 2800 * 256;   // 0..20479
        int h = i / DOUT;
        int o = i - h * DOUT;
        WoT[i] = W_out[o * H + h];
    }
}

// ---------------- prep: bitpack spikes ----------------
__global__ void prep_bits(const float* __restrict__ spk,
                          u64* __restrict__ bits) {
    int b  = blockIdx.x >> 2;
    int wc = blockIdx.x & 3;
    int t  = threadIdx.x;
    if (t >= T) return;
    int w0 = wc * 3;
    int w1 = (wc == 3) ? NW_IN : w0 + 3;
    const float* base = spk + (size_t)b * DIN * T + t;
    for (int w = w0; w < w1; ++w) {
        u64 m = 0;
#pragma unroll
        for (int j = 0; j < 64; ++j) {
            int d = (w << 6) + j;
            if (d < DIN) {
                float x = base[(size_t)d * T];
                m |= (u64)(x > 0.5f) << j;
            }
        }
        bits[((size_t)b * T + t) * NW_INP + w] = m;
    }
}

// ---------------- prep: 4 packed sublists of pre-swizzled LDS byte offsets ----
// Sublist p: j in [175p, 175p+175), local jl = j-175p. Entry = jl*128 +
// ((jl&7)<<4); lane address = entry ^ (li<<4). Each sublist padded to a
// multiple of 4 with JSENT2 (zero row 175). nrow packs 4 chunk counts (u8).
__global__ void __launch_bounds__(256)
prep_lists2(const u64* __restrict__ bits,
            unsigned short* __restrict__ lists,
            unsigned* __restrict__ nrow) {
    __shared__ unsigned short scr[4][LMAX];

    int wv   = threadIdx.x >> 6;
    int lane = threadIdx.x & 63;
    int row  = blockIdx.x * 4 + wv;   // 16000 blocks -> exactly 64000 rows

    const u64* wp = bits + (size_t)row * NW_INP;
    u64 mw = (lane < NW_IN) ? wp[lane] : 0ull;

    for (int i = lane; i < LMAX; i += 64) scr[wv][i] = (unsigned short)JSENT2;

    u64 lowmask = (1ull << lane) - 1ull;
    int pos = 0;
    unsigned counts = 0;

#pragma unroll
    for (int p = 0; p < 4; ++p) {
        int jlo = 175 * p, jhi = jlo + 175;
        int n = 0;
        for (int k = jlo >> 6; k <= (jhi - 1) >> 6; ++k) {
            u64 m = __shfl(mw, k);
            int lo = jlo - (k << 6);
            int hi = jhi - (k << 6);
            if (lo > 0)  m &= ~((1ull << lo) - 1ull);
            if (hi < 64) m &= (1ull << hi) - 1ull;
            if ((m >> lane) & 1ull) {
                int q = pos + n + __popcll(m & lowmask);
                int jl = (k << 6) + lane - jlo;
                if (q < LMAX)
                    scr[wv][q] = (unsigned short)(jl * 128 + ((jl & 7) << 4));
            }
            n += __popcll(m);
        }
        int c = (n + 3) >> 2;           // chunks of 4
        counts |= (unsigned)c << (8 * p);
        pos += c * 4;
    }

    if (lane == 0) nrow[row] = counts;
    __syncthreads();

    const unsigned* s32 = (const unsigned*)scr[wv];
    unsigned* g32 = (unsigned*)(lists + (size_t)row * LMAX);
    g32[lane] = s32[lane];
    if (lane < 16) g32[64 + lane] = s32[64 + lane];
}

// ---------------- prep: counting sort per (b, sublist, t-half) ----------------
__global__ void __launch_bounds__(256)
sort_rows(const unsigned* __restrict__ nrow,
          unsigned char* __restrict__ perm) {
    __shared__ int cnt[8][32];
    __shared__ int off[8][32];
    int b = blockIdx.x, tid = threadIdx.x;
    cnt[tid >> 5][tid & 31] = 0;
    __syncthreads();
    unsigned cc = 0; int half = 0, lt = 0;
    if (tid < T) {
        cc = nrow[b * T + tid];
        half = tid >= 125;
        lt = tid - half * 125;
#pragma unroll
        for (int p = 0; p < 4; ++p) {
            int c = (cc >> (8 * p)) & 0xff; if (c > 31) c = 31;
            atomicAdd(&cnt[p * 2 + half][c], 1);
        }
    }
    __syncthreads();
    if (tid < 8) {
        int s = 0;
        for (int i = 0; i < 32; ++i) { off[tid][i] = s; s += cnt[tid][i]; cnt[tid][i] = 0; }
    }
    __syncthreads();
    if (tid < T) {
#pragma unroll
        for (int p = 0; p < 4; ++p) {
            int c = (cc >> (8 * p)) & 0xff; if (c > 31) c = 31;
            int sidx = p * 2 + half;
            int rank = off[sidx][c] + atomicAdd(&cnt[sidx][c], 1);
            perm[((size_t)b * 8 + sidx) * 128 + rank] = (unsigned char)lt;
        }
    }
}

// ---------------- hidden layer: 38.5 KB LDS -> 4 blocks/CU (32 waves/CU) ----
// (unchanged from round 7 — measured at its DS-port structural floor)
__global__ void __launch_bounds__(512, 8)
hidden_slice3(const unsigned short* __restrict__ lists,
              const unsigned* __restrict__ nrow,
              const unsigned char* __restrict__ perm,
              const float* __restrict__ Wt,
              const float* __restrict__ hs0,
              const float* __restrict__ hv0,
              u64* __restrict__ hsbits) {
    __shared__ float wlds[176 * 32];   // 22,528 B (row 175 = zeros)
    __shared__ float cur[125 * 32];    // 16,000 B

    int s    = blockIdx.x;        // 0..31 h-slice
    int b    = blockIdx.y;        // 0..255
    int tid  = threadIdx.x;
    int wv   = tid >> 6;
    int lane = tid & 63;
    int g    = lane >> 3;
    int li   = lane & 7;
    int lxor = li << 4;
    int l    = lane & 31;

    float keep = 0.0f;
    if (wv == 0) {
        int h = s * 32 + l;
        keep = hv0[b * H + h] * 0.5f * (1.0f - hs0[b * H + h]);
    }
    unsigned* hp = (unsigned*)hsbits;

    for (int th = 0; th < 2; ++th) {
        for (int p = 0; p < 4; ++p) {
            // ---- stage quarter-Wt slice, swizzled: slot = lis ^ (jl&7) ----
            {
                int jr  = tid >> 3;            // 0..63
                int lis = tid & 7;
#pragma unroll
                for (int bj = 0; bj < 192; bj += 64) {
                    int jl = bj + jr;
                    if (jl < 176) {
                        float4 v = make_float4(0.0f, 0.0f, 0.0f, 0.0f);
                        if (jl < 175)
                            v = *(const float4*)(Wt + (size_t)(p * 175 + jl) * H + s * 32 + lis * 4);
                        *(float4*)((char*)wlds + jl * 128 + ((lis ^ (jl & 7)) << 4)) = v;
                    }
                }
            }
            __syncthreads();

            const unsigned char* pm = perm + ((size_t)b * 8 + p * 2 + th) * 128;

            // ---- gather: 125 rows, 64 groups -> 2 sweeps ----
#pragma unroll
            for (int sweep = 0; sweep < 2; ++sweep) {
                int rr = sweep * 64 + wv * 8 + g;
                if (rr < 125) {
                    int lr  = pm[rr];
                    int r   = th * 125 + lr;
                    int row = b * T + r;
                    unsigned cc = nrow[row];
                    int c = (cc >> (8 * p)) & 0xff;
                    int offc = 0;
                    if (p > 0) offc += (cc & 0xff);
                    if (p > 1) offc += ((cc >> 8) & 0xff);
                    if (p > 2) offc += ((cc >> 16) & 0xff);
                    const uint2* qp = (const uint2*)(lists + (size_t)row * LMAX + offc * 4);
                    char* cp = (char*)cur + lr * 128 + ((li ^ (lr & 7)) << 4);

                    float a0, a1, a2, a3;
                    if (p == 0) {
                        a0 = a1 = a2 = a3 = 0.0f;
                    } else {
                        float4 cv = *(const float4*)cp;
                        a0 = cv.x; a1 = cv.y; a2 = cv.z; a3 = cv.w;
                    }

                    if (c > 0) {
                        uint2 w2 = qp[0];
                        int ch = 0;
                        for (;;) {
                            uint2 nw = (ch + 1 < c) ? qp[ch + 1] : w2;
                            int e0 = w2.x & 0xffff, e1 = w2.x >> 16;
                            int e2 = w2.y & 0xffff, e3 = w2.y >> 16;
                            float4 v0 = *(const float4*)((char*)wlds + (e0 ^ lxor));
                            float4 v1 = *(const float4*)((char*)wlds + (e1 ^ lxor));
                            float4 v2 = *(const float4*)((char*)wlds + (e2 ^ lxor));
                            float4 v3 = *(const float4*)((char*)wlds + (e3 ^ lxor));
                            a0 += v0.x; a1 += v0.y; a2 += v0.z; a3 += v0.w;
                            a0 += v1.x; a1 += v1.y; a2 += v1.z; a3 += v1.w;
                            a0 += v2.x; a1 += v2.y; a2 += v2.z; a3 += v2.w;
                            a0 += v3.x; a1 += v3.y; a2 += v3.z; a3 += v3.w;
                            ++ch;
                            if (ch >= c) break;
                            w2 = nw;
                        }
                    }
                    float4 o; o.x = a0; o.y = a1; o.z = a2; o.w = a3;
                    *(float4*)cp = o;
                }
            }
            __syncthreads();
        }

        // ---- scan this t-half: wave 0 (lanes 32-63 mirror), 32 h ----
        if (wv == 0) {
            for (int lt = 0; lt < 125; ++lt) {
                float cv = *(const float*)((char*)cur + lt * 128 +
                                           (((l >> 2) ^ (lt & 7)) << 4) + (l & 3) * 4);
                float hv = keep + cv;
                bool sp = hv > 0.5f;
                keep = sp ? 0.0f : hv * 0.5f;
                u64 ball = __ballot(sp);
                int t = th * 125 + lt;
                if (lane == 0)
                    hp[(size_t)(b * T + t) * 32 + s] = (unsigned)ball;
            }
        }
        __syncthreads();   // protect cur before next half overwrites
    }
}

// ---------------- fallback: round-0 fused hidden kernel (proven) ----------------
__global__ void __launch_bounds__(1024)
hidden_fused(const u64* __restrict__ bits,
             const float* __restrict__ Wt,
             const float* __restrict__ hs0,
             const float* __restrict__ hv0,
             u64* __restrict__ hsbits) {
    __shared__ int idx_l[2][256];

    int b = blockIdx.x;
    int h = threadIdx.x;
    int wv   = h >> 6;
    int lane = h & 63;

    float keep = hv0[b * H + h] * 0.5f * (1.0f - hs0[b * H + h]);

    const u64* bb = bits + (size_t)b * T * NW_INP;

    for (int t = 0; t < T; ++t) {
        const u64* wp = bb + (size_t)t * NW_INP;
        u64 w[NW_IN];
#pragma unroll
        for (int k = 0; k < NW_IN; ++k) w[k] = wp[k];

        int base[NW_IN + 1];
        base[0] = 0;
#pragma unroll
        for (int k = 0; k < NW_IN; ++k) base[k + 1] = base[k] + __popcll(w[k]);
        int n = base[NW_IN];

        int buf = t & 1;
        if (wv < NW_IN) {
            u64 m = w[wv];
            if ((m >> lane) & 1ull) {
                int pos = base[wv] + __popcll(m & ((1ull << lane) - 1ull));
                idx_l[buf][pos] = (wv << 6) + lane;
            }
        }
        __syncthreads();

        const int* il = idx_l[buf];
        float cur2 = 0.0f;
        int i = 0;
        for (; i + 8 <= n; i += 8) {
            int j0 = il[i + 0], j1 = il[i + 1], j2 = il[i + 2], j3 = il[i + 3];
            int j4 = il[i + 4], j5 = il[i + 5], j6 = il[i + 6], j7 = il[i + 7];
            float v0 = Wt[(size_t)j0 * H + h];
            float v1 = Wt[(size_t)j1 * H + h];
            float v2 = Wt[(size_t)j2 * H + h];
            float v3 = Wt[(size_t)j3 * H + h];
            float v4 = Wt[(size_t)j4 * H + h];
            float v5 = Wt[(size_t)j5 * H + h];
            float v6 = Wt[(size_t)j6 * H + h];
            float v7 = Wt[(size_t)j7 * H + h];
            cur2 += v0; cur2 += v1; cur2 += v2; cur2 += v3;
            cur2 += v4; cur2 += v5; cur2 += v6; cur2 += v7;
        }
        for (; i < n; ++i) cur2 += Wt[(size_t)il[i] * H + h];

        float hv = keep + cur2;
        bool sp = hv > 0.5f;
        keep = sp ? 0.0f : hv * 0.5f;
        u64 ball = __ballot(sp);
        if (lane == 0)
            hsbits[((size_t)b * T + t) * NW_H + wv] = ball;
    }
}

// ---------------- output currents v2: LDS-staged WoT, 3 rows/wave ----------------
// Block: 512 threads, WoT (80 KB) staged once. lane = sub*20 + o (sub<3; 60/64
// lanes active). Each 20-lane subgroup walks its row's 16 hsbits words with a
// per-lane ctz bit-loop (subgroup-uniform masks -> no intra-subgroup
// divergence) and accumulates wot[h*20+o] in ascending-h sequential order —
// identical summation order to the previous kernel -> bit-exact.
__global__ void __launch_bounds__(512)
out_currents2(const u64* __restrict__ hsbits,
              const float* __restrict__ WoT,
              float* __restrict__ Iout) {
    __shared__ float wot[H * DOUT];   // 81,920 B

    int tid = threadIdx.x;
    {
        const float4* src = (const float4*)WoT;
        float4* dst = (float4*)wot;
#pragma unroll
        for (int k = 0; k < 10; ++k)
            dst[k * 512 + tid] = src[k * 512 + tid];
    }
    __syncthreads();

    int wv   = tid >> 6;
    int lane = tid & 63;
    int sub  = lane / 20;             // 0..3 (3 = idle)
    int o    = lane - sub * 20;
    int row  = blockIdx.x * 24 + wv * 3 + sub;
    if (sub >= 3 || row >= B * T) return;

    const u64* wp = hsbits + (size_t)row * NW_H;
    u64 w[NW_H];
#pragma unroll
    for (int k = 0; k < NW_H; ++k) w[k] = wp[k];

    float acc = 0.0f;
#pragma unroll
    for (int k = 0; k < NW_H; ++k) {
        u64 m = w[k];
        const float* base = wot + k * 64 * DOUT + o;
        while (m) {
            int h0 = __builtin_ctzll(m);
            m &= m - 1;
            acc += base[h0 * DOUT];
        }
    }
    Iout[(size_t)row * DOUT + o] = acc;
}

// ---------------- output scan + spike count (LDS-staged) ----------------
__global__ void __launch_bounds__(256)
out_scan(const float* __restrict__ Iout,
         const float* __restrict__ os0,
         const float* __restrict__ ov0,
         float* __restrict__ outp) {
    __shared__ float pan[T * DOUT];   // 20,000 B

    int b   = blockIdx.x;
    int tid = threadIdx.x;

    const float* src = Iout + (size_t)b * T * DOUT;
#pragma unroll
    for (int k = 0; k < 20; ++k) {
        int i = k * 256 + tid;
        if (i < T * DOUT) pan[i] = src[i];
    }
    __syncthreads();

    if (tid < DOUT) {
        int o = tid;
        int idx = b * DOUT + o;
        float ov = ov0[idx];
        float os = os0[idx];
        float keep = ov * 0.5f * (1.0f - os);
        float cnt = 0.0f;
#pragma unroll 5
        for (int t = 0; t < T; ++t) {
            float v = keep + pan[t * DOUT + o];
            float sp = (v > 0.5f) ? 1.0f : 0.0f;
            cnt += sp;
            keep = v * 0.5f * (1.0f - sp);
        }
        outp[idx] = cnt;
    }
}

extern "C" void kernel_launch(void* const* d_in, const int* in_sizes, int n_in,
                              void* d_out, int out_size, void* d_ws, size_t ws_size,
                              hipStream_t stream) {
    const float* spike = (const float*)d_in[0];   // [256][700][250]
    const float* W_hid = (const float*)d_in[1];   // [1024][700]
    const float* W_out = (const float*)d_in[2];   // [20][1024]
    const float* hs0   = (const float*)d_in[3];   // [256][1024]
    const float* hv0   = (const float*)d_in[4];
    const float* os0   = (const float*)d_in[5];   // [256][20]
    const float* ov0   = (const float*)d_in[6];
    float* outp = (float*)d_out;                  // [256][20]

    char* ws = (char*)d_ws;
    float*          Wt     = (float*)(ws);                      // 2,867,200 B
    float*          WoT    = (float*)(ws + 2867200);            //    81,920 B
    u64*            bits   = (u64*)  (ws + 2949120);            // 6,144,000 B
    u64*            hsbits = (u64*)  (ws + 9093120);            // 8,192,000 B
    float*          Iout   = (float*)(ws + 17285120);           // 5,120,000 B
    unsigned short* lists  = (unsigned short*)(ws + 22405120);  // 20,480,000 B
    unsigned*       nrow   = (unsigned*)(ws + 42885120);        //   256,000 B
    unsigned char*  perm   = (unsigned char*)(ws + 43141120);   //   262,144 B
    const size_t need = 43403264;

    prep_weights<<<2880, 256, 0, stream>>>(W_hid, W_out, Wt, WoT);
    prep_bits<<<1024, 256, 0, stream>>>(spike, bits);

    if (ws_size >= need) {
        prep_lists2<<<16000, 256, 0, stream>>>(bits, lists, nrow);
        sort_rows<<<B, 256, 0, stream>>>(nrow, perm);
        hidden_slice3<<<dim3(32, 256), 512, 0, stream>>>(lists, nrow, perm, Wt, hs0, hv0, hsbits);
    } else {
        hidden_fused<<<B, 1024, 0, stream>>>(bits, Wt, hs0, hv0, hsbits);
    }

    out_currents2<<<2667, 512, 0, stream>>>(hsbits, WoT, Iout);
    out_scan<<<B, 256, 0, stream>>>(Iout, os0, ov0, outp);
}